// Round 3
// baseline (362.813 us; speedup 1.0000x reference)
//
#include <hip/hip_runtime.h>
#include <hip/hip_bf16.h>

// GCN pipeline on MI355X — MFMA bf16 GEMMs, fp32 accumulate, bf16 dataflow.
// R10: gemm1 rewritten barrier-free. Post-mortem R7/R9: both stagings pinned at
//      ~57us with ALL pipes idle -> block latency 45K cyc dominated by 9 barrier
//      round-trips + A-LDS traffic + per-kc Wt re-staging. New structure:
//      - A: direct global->reg (lane-own-row 32B slices; L1/L2 serves the 2x reuse)
//      - B: full Wt (64KB) in LDS once, XOR-swizzled ((row&7)<<4), ONE barrier
//      - 128-row tiles, 8 waves = 4 rowgrp x 2 colhalf, 64 MFMA/thread, no sync
//        in the K-loop. K=239 tail via in-row overlapping loads (never OOB).
//      agg_k (4+2+1 unroll) and mgemm_k unchanged.

typedef __attribute__((ext_vector_type(8))) __bf16 bf16x8;
typedef __attribute__((ext_vector_type(4))) float f32x4;
// 4B-aligned float4 (x rows are 956B-strided: only dword-aligned)
typedef float f32x4u __attribute__((ext_vector_type(4), aligned(4)));

// All 3 weight transposes in one dispatch.
// seg0: W_in [ND][128] -> Wt_in [128][256] (zero pad k>=ND)
// seg1: W_g  [128][128] -> Wt_g  [128][128]
// seg2: W_o1 [128][128] -> Wt_o1 [128][128]
__global__ __launch_bounds__(256) void wtr_all_k(const float* __restrict__ W_in,
                                                 const float* __restrict__ W_g,
                                                 const float* __restrict__ W_o1,
                                                 ushort* __restrict__ Wt_in,
                                                 ushort* __restrict__ Wt_g,
                                                 ushort* __restrict__ Wt_o1, int ND) {
  int idx = blockIdx.x * 256 + threadIdx.x;
  if (idx < 128 * 256) {
    int n = idx >> 8, k = idx & 255;
    float v = (k < ND) ? W_in[(size_t)k * 128 + n] : 0.f;
    __hip_bfloat16 h = __float2bfloat16(v);
    Wt_in[idx] = *(ushort*)&h;
  } else if (idx < 128 * 256 + 128 * 128) {
    int j = idx - 128 * 256;
    int n = j >> 7, k = j & 127;
    __hip_bfloat16 h = __float2bfloat16(W_g[(size_t)k * 128 + n]);
    Wt_g[j] = *(ushort*)&h;
  } else if (idx < 128 * 256 + 2 * 128 * 128) {
    int j = idx - 128 * 256 - 128 * 128;
    int n = j >> 7, k = j & 127;
    __hip_bfloat16 h = __float2bfloat16(W_o1[(size_t)k * 128 + n]);
    Wt_o1[j] = *(ushort*)&h;
  }
}

// ---------------- CSR build ----------------

__global__ __launch_bounds__(256) void zero_k(int* __restrict__ p, int n) {
  int i = blockIdx.x * 256 + threadIdx.x;
  if (i < n) p[i] = 0;
}

__global__ __launch_bounds__(256) void hist_k(const int* __restrict__ dst, int* __restrict__ cnt, int E) {
  int e = blockIdx.x * 256 + threadIdx.x;
  if (e < E) atomicAdd(&cnt[dst[e]], 1);
}

__global__ __launch_bounds__(256) void scan1_k(const int* __restrict__ cnt, int* __restrict__ rp,
                                               int* __restrict__ bsum, int N) {
  __shared__ int sd[256];
  int t = threadIdx.x;
  int base = blockIdx.x * 1024 + t * 4;
  int v0 = (base + 0 < N) ? cnt[base + 0] : 0;
  int v1 = (base + 1 < N) ? cnt[base + 1] : 0;
  int v2 = (base + 2 < N) ? cnt[base + 2] : 0;
  int v3 = (base + 3 < N) ? cnt[base + 3] : 0;
  int ts = v0 + v1 + v2 + v3;
  sd[t] = ts;
  __syncthreads();
  for (int off = 1; off < 256; off <<= 1) {
    int y = (t >= off) ? sd[t - off] : 0;
    __syncthreads();
    sd[t] += y;
    __syncthreads();
  }
  int x = sd[t] - ts;
  if (t == 255) bsum[blockIdx.x] = sd[255];
  if (base + 0 < N) rp[base + 0] = x; x += v0;
  if (base + 1 < N) rp[base + 1] = x; x += v1;
  if (base + 2 < N) rp[base + 2] = x; x += v2;
  if (base + 3 < N) rp[base + 3] = x;
}

__global__ __launch_bounds__(256) void scan2_k(int* __restrict__ bsum, int NB) {
  __shared__ int sd[256];
  int t = threadIdx.x;
  int base = t * 4;
  int v0 = (base + 0 < NB) ? bsum[base + 0] : 0;
  int v1 = (base + 1 < NB) ? bsum[base + 1] : 0;
  int v2 = (base + 2 < NB) ? bsum[base + 2] : 0;
  int v3 = (base + 3 < NB) ? bsum[base + 3] : 0;
  int ts = v0 + v1 + v2 + v3;
  sd[t] = ts;
  __syncthreads();
  for (int off = 1; off < 256; off <<= 1) {
    int y = (t >= off) ? sd[t - off] : 0;
    __syncthreads();
    sd[t] += y;
    __syncthreads();
  }
  int x = sd[t] - ts;
  if (base + 0 < NB) bsum[base + 0] = x; x += v0;
  if (base + 1 < NB) bsum[base + 1] = x; x += v1;
  if (base + 2 < NB) bsum[base + 2] = x; x += v2;
  if (base + 3 < NB) bsum[base + 3] = x;
}

__global__ __launch_bounds__(256) void scan3_k(int* __restrict__ rp, int* __restrict__ pos,
                                               const int* __restrict__ bsum,
                                               float* __restrict__ dinv, int N, int E) {
  int i = blockIdx.x * 256 + threadIdx.x;
  if (i < N) {
    int c = pos[i];  // pos aliases cnt: still the original count here
    int v = rp[i] + bsum[i >> 10];
    dinv[i] = rsqrtf((float)c + 1.0f);
    rp[i] = v;
    pos[i] = v;
  }
  if (i == 0) rp[N] = E;
}

__global__ __launch_bounds__(256) void fill_k(const int* __restrict__ src, const int* __restrict__ dst,
                                              const float* __restrict__ dinv,
                                              int* __restrict__ pos, int2* __restrict__ ew, int E) {
  int e = blockIdx.x * 256 + threadIdx.x;
  if (e < E) {
    int d = dst[e];
    int s = src[e];
    int idx = atomicAdd(&pos[d], 1);
    ew[idx] = make_int2(s, __float_as_int(dinv[s] * dinv[d]));
  }
}

// ---------------- GEMM1: hA = leaky(x[N,239] @ Wt^T + bias), bf16 out ----------------

__device__ __forceinline__ bf16x8 cvt8(f32x4u lo, f32x4u hi) {
  bf16x8 r;
#pragma unroll
  for (int j = 0; j < 4; ++j) {
    __hip_bfloat16 h = __float2bfloat16(lo[j]);
    r[j] = *(__bf16*)&h;
  }
#pragma unroll
  for (int j = 0; j < 4; ++j) {
    __hip_bfloat16 h = __float2bfloat16(hi[j]);
    r[4 + j] = *(__bf16*)&h;
  }
  return r;
}

// 128 rows x 128 cols per block, 512 thr = 8 waves (4 rowgrp x 2 colhalf).
// A: global->reg, lane-own-row. B: full Wt in LDS (swizzled), staged once.
__global__ __launch_bounds__(512, 4) void gemm1_k(const float* __restrict__ x,
                                                  const ushort* __restrict__ Wt,
                                                  const float* __restrict__ bias,
                                                  ushort* __restrict__ C, int N, int Ka) {
  __shared__ char Wb[65536];  // Wt [128][256] bf16, byte ^= (row&7)<<4
  const int tid = threadIdx.x;
  const int wave = tid >> 6;
  const int lane = tid & 63;
  const int l16 = lane & 15;
  const int quad = lane >> 4;
  const int m0 = blockIdx.x * 128;
  const int wr = wave >> 1;  // 0..3 row group (32 rows)
  const int wc = wave & 1;   // 0..1 col half (64 cols)

  // ---- stage full Wt into LDS, swizzled; perfectly coalesced (512B/row) ----
#pragma unroll
  for (int it = 0; it < 8; ++it) {
    int f = it * 512 + tid;          // 0..4095 uint4s
    int row = f >> 5, c32 = f & 31;  // 32 x 16B per row
    uint4 v = *(const uint4*)(Wt + (size_t)row * 256 + c32 * 8);
    int ofs = (row * 512 + c32 * 16) ^ ((row & 7) << 4);
    *(uint4*)(Wb + ofs) = v;
  }
  __syncthreads();  // the only barrier

  // clamped A rows (pad rows duplicate row N-1; their C writes are guarded)
  int rA0 = m0 + wr * 32 + l16;
  int rA1 = rA0 + 16;
  if (rA0 > N - 1) rA0 = N - 1;
  if (rA1 > N - 1) rA1 = N - 1;
  const float* __restrict__ xr0 = x + (size_t)rA0 * Ka;
  const float* __restrict__ xr1 = x + (size_t)rA1 * Ka;

  f32x4 acc[2][4] = {};

#pragma unroll
  for (int t = 0; t < 8; ++t) {
    const int k0 = t * 32 + quad * 8;
    bf16x8 a0, a1;
    if (t < 7 || quad == 0) {
      // full 8 valid elements (k0 <= 224, k0+8 <= 232 <= 239)
      a0 = cvt8(*(const f32x4u*)(xr0 + k0), *(const f32x4u*)(xr0 + k0 + 4));
      a1 = cvt8(*(const f32x4u*)(xr1 + k0), *(const f32x4u*)(xr1 + k0 + 4));
    } else if (quad == 1) {
      // k0 == 232: elements 232..238 valid; overlap trick stays in-row (<= 239*4B)
      f32x4u lo0 = *(const f32x4u*)(xr0 + 232), hi0 = *(const f32x4u*)(xr0 + 235);
      f32x4u lo1 = *(const f32x4u*)(xr1 + 232), hi1 = *(const f32x4u*)(xr1 + 235);
      f32x4u h0 = {hi0[1], hi0[2], hi0[3], 0.f};
      f32x4u h1 = {hi1[1], hi1[2], hi1[3], 0.f};
      a0 = cvt8(lo0, h0);
      a1 = cvt8(lo1, h1);
    } else {
      a0 = bf16x8{};  // k >= 240: Wt rows are zero too
      a1 = bf16x8{};
    }
    const int kb = t * 64 + quad * 16;  // byte offset of k within a Wt row
#pragma unroll
    for (int c = 0; c < 4; ++c) {
      const int brow = wc * 64 + c * 16 + l16;
      bf16x8 b = *(const bf16x8*)(Wb + ((brow * 512 + kb) ^ ((brow & 7) << 4)));
      acc[0][c] = __builtin_amdgcn_mfma_f32_16x16x32_bf16(a0, b, acc[0][c], 0, 0, 0);
      acc[1][c] = __builtin_amdgcn_mfma_f32_16x16x32_bf16(a1, b, acc[1][c], 0, 0, 0);
    }
  }

  float bv[4];
#pragma unroll
  for (int c = 0; c < 4; ++c) bv[c] = bias[wc * 64 + c * 16 + l16];
#pragma unroll
  for (int rt = 0; rt < 2; ++rt) {
#pragma unroll
    for (int reg = 0; reg < 4; ++reg) {
      int row = m0 + wr * 32 + rt * 16 + quad * 4 + reg;
      if (row < N) {
#pragma unroll
        for (int c = 0; c < 4; ++c) {
          float v = acc[rt][c][reg] + bv[c];
          v = v >= 0.f ? v : 0.01f * v;
          __hip_bfloat16 h = __float2bfloat16(v);
          C[(size_t)row * 128 + wc * 64 + c * 16 + l16] = *(ushort*)&h;
        }
      }
    }
  }
}

// ---------------- MFMA GEMM (bf16 A, K=128): C = A @ Wt^T ----------------
// MODE: 1 = bf16 + bias; 3 = fused leaky(.+bias)@W2 + b2 -> out[N,2] f32.

template <int MODE>
__global__ __launch_bounds__(512, 4) void mgemm_k(const ushort* __restrict__ A,
                                                  const ushort* __restrict__ Wt,
                                                  const float* __restrict__ bias,
                                                  const float* __restrict__ W2,
                                                  const float* __restrict__ b2,
                                                  void* __restrict__ C, int N) {
  __shared__ uint4 Al[128 * 16];
  __shared__ uint4 Wl[128 * 16];
  const int tid = threadIdx.x;
  const int wave = tid >> 6;
  const int lane = tid & 63;
  const int l16 = lane & 15;
  const int quad = lane >> 4;
  const int m0 = blockIdx.x * 128;

  f32x4 acc[8] = {};
  const int r_s = tid >> 4;
  const int j8 = tid & 15;
#pragma unroll
  for (int it = 0; it < 4; ++it) {
    int m = it * 32 + r_s;
    Al[m * 16 + (j8 ^ (m & 15))] = *(const uint4*)(A + (size_t)(m0 + m) * 128 + j8 * 8);
  }
#pragma unroll
  for (int it = 0; it < 4; ++it) {
    int n = it * 32 + r_s;
    Wl[n * 16 + (j8 ^ (n & 15))] = *(const uint4*)(Wt + (size_t)n * 128 + j8 * 8);
  }
  __syncthreads();
#pragma unroll
  for (int s = 0; s < 4; ++s) {
    const int j = s * 4 + quad;
    const int arow = wave * 16 + l16;
    bf16x8 a = *(const bf16x8*)&Al[arow * 16 + (j ^ (arow & 15))];
#pragma unroll
    for (int c = 0; c < 8; ++c) {
      const int brow = c * 16 + l16;
      bf16x8 b = *(const bf16x8*)&Wl[brow * 16 + (j ^ (brow & 15))];
      acc[c] = __builtin_amdgcn_mfma_f32_16x16x32_bf16(a, b, acc[c], 0, 0, 0);
    }
  }

  float bv[8];
#pragma unroll
  for (int c = 0; c < 8; ++c) bv[c] = bias[c * 16 + l16];

  if constexpr (MODE == 3) {
    float w20[8], w21[8];
#pragma unroll
    for (int c = 0; c < 8; ++c) {
      int colj = c * 16 + l16;
      w20[c] = W2[colj * 2 + 0];
      w21[c] = W2[colj * 2 + 1];
    }
    float bb0 = b2[0], bb1 = b2[1];
#pragma unroll
    for (int reg = 0; reg < 4; ++reg) {
      float o0 = 0.f, o1 = 0.f;
#pragma unroll
      for (int c = 0; c < 8; ++c) {
        float v = acc[c][reg] + bv[c];
        v = v >= 0.f ? v : 0.01f * v;
        o0 = fmaf(v, w20[c], o0);
        o1 = fmaf(v, w21[c], o1);
      }
      o0 += __shfl_xor(o0, 1); o0 += __shfl_xor(o0, 2);
      o0 += __shfl_xor(o0, 4); o0 += __shfl_xor(o0, 8);
      o1 += __shfl_xor(o1, 1); o1 += __shfl_xor(o1, 2);
      o1 += __shfl_xor(o1, 4); o1 += __shfl_xor(o1, 8);
      int row = m0 + wave * 16 + quad * 4 + reg;
      if (l16 == 0 && row < N)
        *(float2*)((float*)C + (size_t)row * 2) = make_float2(o0 + bb0, o1 + bb1);
    }
    return;
  }

#pragma unroll
  for (int reg = 0; reg < 4; ++reg) {
    int row = m0 + wave * 16 + quad * 4 + reg;
    if (row < N) {
#pragma unroll
      for (int c = 0; c < 8; ++c) {
        float v = acc[c][reg] + bv[c];
        __hip_bfloat16 h = __float2bfloat16(v);
        ((ushort*)C)[(size_t)row * 128 + c * 16 + l16] = *(ushort*)&h;
      }
    }
  }
}

// ---------------- CSR-pull aggregation, bf16 -> bf16 ----------------
// Edge loop unrolled 4 (+2 +1 tail) so each 16-lane group keeps up to
// 4 independent 256B row-gathers in flight (latency hiding).

__global__ __launch_bounds__(256) void agg_k(const ushort* __restrict__ T,
                                             const float* __restrict__ dinv,
                                             const int* __restrict__ rp,
                                             const int2* __restrict__ ew,
                                             ushort* __restrict__ O, int N) {
  int l = threadIdx.x & 15;
  int node = blockIdx.x * 16 + (threadIdx.x >> 4);
  if (node >= N) return;
  float di = dinv[node];
  float dsq = di * di;
  const uint4* T4 = (const uint4*)T;
  float a[8];
  {
    uint4 sv = T4[(size_t)node * 16 + l];
    uint u[4] = {sv.x, sv.y, sv.z, sv.w};
#pragma unroll
    for (int p = 0; p < 4; ++p) {
      a[2 * p + 0] = __uint_as_float(u[p] << 16) * dsq;
      a[2 * p + 1] = __uint_as_float(u[p] & 0xFFFF0000u) * dsq;
    }
  }
  int e = rp[node];
  const int e1 = rp[node + 1];
  for (; e + 4 <= e1; e += 4) {
    int2 p0 = ew[e + 0], p1 = ew[e + 1], p2 = ew[e + 2], p3 = ew[e + 3];
    uint4 v0 = T4[(size_t)p0.x * 16 + l];
    uint4 v1 = T4[(size_t)p1.x * 16 + l];
    uint4 v2 = T4[(size_t)p2.x * 16 + l];
    uint4 v3 = T4[(size_t)p3.x * 16 + l];
    float w0 = __int_as_float(p0.y), w1 = __int_as_float(p1.y);
    float w2 = __int_as_float(p2.y), w3 = __int_as_float(p3.y);
    uint u0[4] = {v0.x, v0.y, v0.z, v0.w};
    uint u1[4] = {v1.x, v1.y, v1.z, v1.w};
    uint u2[4] = {v2.x, v2.y, v2.z, v2.w};
    uint u3[4] = {v3.x, v3.y, v3.z, v3.w};
#pragma unroll
    for (int p = 0; p < 4; ++p) {
      a[2 * p + 0] = fmaf(__uint_as_float(u0[p] << 16), w0, a[2 * p + 0]);
      a[2 * p + 1] = fmaf(__uint_as_float(u0[p] & 0xFFFF0000u), w0, a[2 * p + 1]);
      a[2 * p + 0] = fmaf(__uint_as_float(u1[p] << 16), w1, a[2 * p + 0]);
      a[2 * p + 1] = fmaf(__uint_as_float(u1[p] & 0xFFFF0000u), w1, a[2 * p + 1]);
      a[2 * p + 0] = fmaf(__uint_as_float(u2[p] << 16), w2, a[2 * p + 0]);
      a[2 * p + 1] = fmaf(__uint_as_float(u2[p] & 0xFFFF0000u), w2, a[2 * p + 1]);
      a[2 * p + 0] = fmaf(__uint_as_float(u3[p] << 16), w3, a[2 * p + 0]);
      a[2 * p + 1] = fmaf(__uint_as_float(u3[p] & 0xFFFF0000u), w3, a[2 * p + 1]);
    }
  }
  if (e + 2 <= e1) {
    int2 p0 = ew[e + 0], p1 = ew[e + 1];
    uint4 v0 = T4[(size_t)p0.x * 16 + l];
    uint4 v1 = T4[(size_t)p1.x * 16 + l];
    float w0 = __int_as_float(p0.y), w1 = __int_as_float(p1.y);
    uint u0[4] = {v0.x, v0.y, v0.z, v0.w};
    uint u1[4] = {v1.x, v1.y, v1.z, v1.w};
#pragma unroll
    for (int p = 0; p < 4; ++p) {
      a[2 * p + 0] = fmaf(__uint_as_float(u0[p] << 16), w0, a[2 * p + 0]);
      a[2 * p + 1] = fmaf(__uint_as_float(u0[p] & 0xFFFF0000u), w0, a[2 * p + 1]);
      a[2 * p + 0] = fmaf(__uint_as_float(u1[p] << 16), w1, a[2 * p + 0]);
      a[2 * p + 1] = fmaf(__uint_as_float(u1[p] & 0xFFFF0000u), w1, a[2 * p + 1]);
    }
    e += 2;
  }
  if (e < e1) {
    int2 pw = ew[e];
    float w = __int_as_float(pw.y);
    uint4 v = T4[(size_t)pw.x * 16 + l];
    uint u[4] = {v.x, v.y, v.z, v.w};
#pragma unroll
    for (int p = 0; p < 4; ++p) {
      a[2 * p + 0] = fmaf(__uint_as_float(u[p] << 16), w, a[2 * p + 0]);
      a[2 * p + 1] = fmaf(__uint_as_float(u[p] & 0xFFFF0000u), w, a[2 * p + 1]);
    }
  }
  union { uint4 v; ushort s[8]; } uo;
#pragma unroll
  for (int j = 0; j < 8; ++j) {
    __hip_bfloat16 h = __float2bfloat16(a[j]);
    uo.s[j] = *(ushort*)&h;
  }
  ((uint4*)O)[(size_t)node * 16 + l] = uo.v;
}

// ---------------- launch ----------------

extern "C" void kernel_launch(void* const* d_in, const int* in_sizes, int n_in,
                              void* d_out, int out_size, void* d_ws, size_t ws_size,
                              hipStream_t stream) {
  const float* x = (const float*)d_in[0];
  const int* ei = (const int*)d_in[1];
  const float* W_in = (const float*)d_in[3];
  const float* b_in = (const float*)d_in[4];
  const float* W_g  = (const float*)d_in[5];
  const float* b_g  = (const float*)d_in[6];
  const float* W_o1 = (const float*)d_in[7];
  const float* b_o1 = (const float*)d_in[8];
  const float* W_o2 = (const float*)d_in[9];
  const float* b_o2 = (const float*)d_in[10];

  const int D = in_sizes[4];        // 128
  const int ND = in_sizes[3] / D;   // 239
  const int N = in_sizes[0] / ND;   // 100000
  const int E = in_sizes[2];        // 640000
  const int* src = ei;
  const int* dst = ei + E;

  const int N_pad = ((N + 127) / 128) * 128;
  const size_t np = (size_t)N_pad;
  const int KP1 = 256;

  ushort* hA = (ushort*)d_ws;                 // np*128 bf16
  ushort* hB = hA + np * 128;                 // np*128 bf16
  ushort* Wt_in = hB + np * 128;              // 128*256 bf16
  ushort* Wt_g  = Wt_in + 128 * 256;          // 128*128
  ushort* Wt_o1 = Wt_g + 128 * 128;           // 128*128
  float* dinv = (float*)(Wt_o1 + 128 * 128);  // N f32
  int* cnt  = (int*)(dinv + N);
  int* rp   = cnt + N;
  int* bsum = rp + (N + 1);
  int2* ew  = (int2*)(((size_t)(bsum + 1024) + 7) & ~(size_t)7);

  const int NB = (N + 1023) / 1024;

  wtr_all_k<<<(128 * KP1 + 2 * 128 * 128 + 255) / 256, 256, 0, stream>>>(
      W_in, W_g, W_o1, Wt_in, Wt_g, Wt_o1, ND);

  zero_k<<<(N + 255) / 256, 256, 0, stream>>>(cnt, N);
  hist_k<<<(E + 255) / 256, 256, 0, stream>>>(dst, cnt, E);
  scan1_k<<<NB, 256, 0, stream>>>(cnt, rp, bsum, N);
  scan2_k<<<1, 256, 0, stream>>>(bsum, NB);
  scan3_k<<<(N + 255) / 256, 256, 0, stream>>>(rp, cnt /*pos*/, bsum, dinv, N, E);
  fill_k<<<(E + 255) / 256, 256, 0, stream>>>(src, dst, dinv, cnt, ew, E);

  const int gblocks = N_pad / 128;
  const int ablocks = (N + 15) / 16;
  gemm1_k<<<gblocks, 512, 0, stream>>>(x, Wt_in, b_in, hA, N, ND);
  agg_k<<<ablocks, 256, 0, stream>>>(hA, dinv, rp, ew, hB, N);
  mgemm_k<1><<<gblocks, 512, 0, stream>>>(hB, Wt_g, b_g, nullptr, nullptr, hA, N);
  agg_k<<<ablocks, 256, 0, stream>>>(hA, dinv, rp, ew, hB, N);
  mgemm_k<1><<<gblocks, 512, 0, stream>>>(hB, Wt_g, b_g, nullptr, nullptr, hA, N);
  mgemm_k<3><<<gblocks, 512, 0, stream>>>(hA, Wt_o1, b_o1, W_o2, b_o2, d_out, N);
}

// Round 4
// 360.753 us; speedup vs baseline: 1.0057x; 1.0057x over previous
//
#include <hip/hip_runtime.h>
#include <hip/hip_bf16.h>

// GCN pipeline on MI355X — MFMA bf16 GEMMs, fp32 accumulate, bf16 dataflow.
// R11: post-mortem R7/R9/R10 — three gemm1 structures all 57-66us, all pipes idle:
//      the f32 x-stream inside the MFMA kernel is outstanding-bytes-starved
//      (52 VGPR -> ~4KB in flight vs ~22KB needed at 900cy HBM latency).
//      Split it: cvt_k streams x f32 -> xb bf16 [N][256] (pure copy pattern,
//      ~6 TB/s regime), then gemm1b_k = proven mgemm structure with K=256
//      (2 kc-chunks, swizzled LDS, 3 barriers). agg/mgemm/CSR unchanged.

typedef __attribute__((ext_vector_type(8))) __bf16 bf16x8;
typedef __attribute__((ext_vector_type(4))) float f32x4;
// 4B-aligned float4 (x rows are 956B-strided: only dword-aligned)
typedef float f32x4u __attribute__((ext_vector_type(4), aligned(4)));

// All 3 weight transposes in one dispatch.
// seg0: W_in [ND][128] -> Wt_in [128][256] (zero pad k>=ND)
// seg1: W_g  [128][128] -> Wt_g  [128][128]
// seg2: W_o1 [128][128] -> Wt_o1 [128][128]
__global__ __launch_bounds__(256) void wtr_all_k(const float* __restrict__ W_in,
                                                 const float* __restrict__ W_g,
                                                 const float* __restrict__ W_o1,
                                                 ushort* __restrict__ Wt_in,
                                                 ushort* __restrict__ Wt_g,
                                                 ushort* __restrict__ Wt_o1, int ND) {
  int idx = blockIdx.x * 256 + threadIdx.x;
  if (idx < 128 * 256) {
    int n = idx >> 8, k = idx & 255;
    float v = (k < ND) ? W_in[(size_t)k * 128 + n] : 0.f;
    __hip_bfloat16 h = __float2bfloat16(v);
    Wt_in[idx] = *(ushort*)&h;
  } else if (idx < 128 * 256 + 128 * 128) {
    int j = idx - 128 * 256;
    int n = j >> 7, k = j & 127;
    __hip_bfloat16 h = __float2bfloat16(W_g[(size_t)k * 128 + n]);
    Wt_g[j] = *(ushort*)&h;
  } else if (idx < 128 * 256 + 2 * 128 * 128) {
    int j = idx - 128 * 256 - 128 * 128;
    int n = j >> 7, k = j & 127;
    __hip_bfloat16 h = __float2bfloat16(W_o1[(size_t)k * 128 + n]);
    Wt_o1[j] = *(ushort*)&h;
  }
}

// ---------------- x f32 -> xb bf16 [N][256] streaming convert ----------------
// One uint4 (8 bf16) per thread-iteration. Reads coalesced (row-sequential),
// writes fully coalesced. Cols >= Ka zero-filled (matches zero-padded Wt_in).

__global__ __launch_bounds__(256) void cvt_k(const float* __restrict__ x,
                                             ushort* __restrict__ xb,
                                             int N, int Ka) {
  const int total = N * 32;  // output uint4s
  const int stride = gridDim.x * 256;
  for (int o = blockIdx.x * 256 + threadIdx.x; o < total; o += stride) {
    const int r = o >> 5, j = o & 31;
    const int k0 = j * 8;
    union { uint4 v; ushort s[8]; } out;
    if (k0 + 8 <= Ka) {
      const float* p = x + (size_t)r * Ka + k0;
      f32x4u lo = *(const f32x4u*)p;
      f32x4u hi = *(const f32x4u*)(p + 4);
#pragma unroll
      for (int t = 0; t < 4; ++t) {
        __hip_bfloat16 h = __float2bfloat16(lo[t]);
        out.s[t] = *(ushort*)&h;
      }
#pragma unroll
      for (int t = 0; t < 4; ++t) {
        __hip_bfloat16 h = __float2bfloat16(hi[t]);
        out.s[4 + t] = *(ushort*)&h;
      }
    } else if (k0 < Ka) {
      const float* p = x + (size_t)r * Ka;
#pragma unroll
      for (int t = 0; t < 8; ++t) {
        float v = (k0 + t < Ka) ? p[k0 + t] : 0.f;
        __hip_bfloat16 h = __float2bfloat16(v);
        out.s[t] = *(ushort*)&h;
      }
    } else {
      out.v = make_uint4(0, 0, 0, 0);
    }
    ((uint4*)xb)[o] = out.v;
  }
}

// ---------------- CSR build ----------------

__global__ __launch_bounds__(256) void zero_k(int* __restrict__ p, int n) {
  int i = blockIdx.x * 256 + threadIdx.x;
  if (i < n) p[i] = 0;
}

__global__ __launch_bounds__(256) void hist_k(const int* __restrict__ dst, int* __restrict__ cnt, int E) {
  int e = blockIdx.x * 256 + threadIdx.x;
  if (e < E) atomicAdd(&cnt[dst[e]], 1);
}

__global__ __launch_bounds__(256) void scan1_k(const int* __restrict__ cnt, int* __restrict__ rp,
                                               int* __restrict__ bsum, int N) {
  __shared__ int sd[256];
  int t = threadIdx.x;
  int base = blockIdx.x * 1024 + t * 4;
  int v0 = (base + 0 < N) ? cnt[base + 0] : 0;
  int v1 = (base + 1 < N) ? cnt[base + 1] : 0;
  int v2 = (base + 2 < N) ? cnt[base + 2] : 0;
  int v3 = (base + 3 < N) ? cnt[base + 3] : 0;
  int ts = v0 + v1 + v2 + v3;
  sd[t] = ts;
  __syncthreads();
  for (int off = 1; off < 256; off <<= 1) {
    int y = (t >= off) ? sd[t - off] : 0;
    __syncthreads();
    sd[t] += y;
    __syncthreads();
  }
  int x = sd[t] - ts;
  if (t == 255) bsum[blockIdx.x] = sd[255];
  if (base + 0 < N) rp[base + 0] = x; x += v0;
  if (base + 1 < N) rp[base + 1] = x; x += v1;
  if (base + 2 < N) rp[base + 2] = x; x += v2;
  if (base + 3 < N) rp[base + 3] = x;
}

__global__ __launch_bounds__(256) void scan2_k(int* __restrict__ bsum, int NB) {
  __shared__ int sd[256];
  int t = threadIdx.x;
  int base = t * 4;
  int v0 = (base + 0 < NB) ? bsum[base + 0] : 0;
  int v1 = (base + 1 < NB) ? bsum[base + 1] : 0;
  int v2 = (base + 2 < NB) ? bsum[base + 2] : 0;
  int v3 = (base + 3 < NB) ? bsum[base + 3] : 0;
  int ts = v0 + v1 + v2 + v3;
  sd[t] = ts;
  __syncthreads();
  for (int off = 1; off < 256; off <<= 1) {
    int y = (t >= off) ? sd[t - off] : 0;
    __syncthreads();
    sd[t] += y;
    __syncthreads();
  }
  int x = sd[t] - ts;
  if (base + 0 < NB) bsum[base + 0] = x; x += v0;
  if (base + 1 < NB) bsum[base + 1] = x; x += v1;
  if (base + 2 < NB) bsum[base + 2] = x; x += v2;
  if (base + 3 < NB) bsum[base + 3] = x;
}

__global__ __launch_bounds__(256) void scan3_k(int* __restrict__ rp, int* __restrict__ pos,
                                               const int* __restrict__ bsum,
                                               float* __restrict__ dinv, int N, int E) {
  int i = blockIdx.x * 256 + threadIdx.x;
  if (i < N) {
    int c = pos[i];  // pos aliases cnt: still the original count here
    int v = rp[i] + bsum[i >> 10];
    dinv[i] = rsqrtf((float)c + 1.0f);
    rp[i] = v;
    pos[i] = v;
  }
  if (i == 0) rp[N] = E;
}

__global__ __launch_bounds__(256) void fill_k(const int* __restrict__ src, const int* __restrict__ dst,
                                              const float* __restrict__ dinv,
                                              int* __restrict__ pos, int2* __restrict__ ew, int E) {
  int e = blockIdx.x * 256 + threadIdx.x;
  if (e < E) {
    int d = dst[e];
    int s = src[e];
    int idx = atomicAdd(&pos[d], 1);
    ew[idx] = make_int2(s, __float_as_int(dinv[s] * dinv[d]));
  }
}

// ---------------- GEMM1b: hA = leaky(xb[N,256]bf16 @ Wt^T + bias), bf16 out ----
// Exact mgemm structure, K=256 in two kc-chunks (Al/Wl reused, 3 barriers).

__global__ __launch_bounds__(512, 4) void gemm1b_k(const ushort* __restrict__ A,
                                                   const ushort* __restrict__ Wt,
                                                   const float* __restrict__ bias,
                                                   ushort* __restrict__ C, int N) {
  __shared__ uint4 Al[128 * 16];
  __shared__ uint4 Wl[128 * 16];
  const int tid = threadIdx.x;
  const int wave = tid >> 6;
  const int lane = tid & 63;
  const int l16 = lane & 15;
  const int quad = lane >> 4;
  const int m0 = blockIdx.x * 128;

  f32x4 acc[8] = {};
  const int r_s = tid >> 4;
  const int j8 = tid & 15;
#pragma unroll
  for (int kc = 0; kc < 2; ++kc) {
    if (kc) __syncthreads();  // Al/Wl reuse: wait for prior MFMA reads
#pragma unroll
    for (int it = 0; it < 4; ++it) {
      int m = it * 32 + r_s;
      Al[m * 16 + (j8 ^ (m & 15))] =
          *(const uint4*)(A + (size_t)(m0 + m) * 256 + kc * 128 + j8 * 8);
    }
#pragma unroll
    for (int it = 0; it < 4; ++it) {
      int n = it * 32 + r_s;
      Wl[n * 16 + (j8 ^ (n & 15))] =
          *(const uint4*)(Wt + (size_t)n * 256 + kc * 128 + j8 * 8);
    }
    __syncthreads();
#pragma unroll
    for (int s = 0; s < 4; ++s) {
      const int j = s * 4 + quad;
      const int arow = wave * 16 + l16;
      bf16x8 a = *(const bf16x8*)&Al[arow * 16 + (j ^ (arow & 15))];
#pragma unroll
      for (int c = 0; c < 8; ++c) {
        const int brow = c * 16 + l16;
        bf16x8 b = *(const bf16x8*)&Wl[brow * 16 + (j ^ (brow & 15))];
        acc[c] = __builtin_amdgcn_mfma_f32_16x16x32_bf16(a, b, acc[c], 0, 0, 0);
      }
    }
  }

  float bv[8];
#pragma unroll
  for (int c = 0; c < 8; ++c) bv[c] = bias[c * 16 + l16];
#pragma unroll
  for (int reg = 0; reg < 4; ++reg) {
    int row = m0 + wave * 16 + quad * 4 + reg;
    if (row < N) {
#pragma unroll
      for (int c = 0; c < 8; ++c) {
        float v = acc[c][reg] + bv[c];
        v = v >= 0.f ? v : 0.01f * v;
        __hip_bfloat16 h = __float2bfloat16(v);
        C[(size_t)row * 128 + c * 16 + l16] = *(ushort*)&h;
      }
    }
  }
}

// ---------------- MFMA GEMM (bf16 A, K=128): C = A @ Wt^T ----------------
// MODE: 1 = bf16 + bias; 3 = fused leaky(.+bias)@W2 + b2 -> out[N,2] f32.

template <int MODE>
__global__ __launch_bounds__(512, 4) void mgemm_k(const ushort* __restrict__ A,
                                                  const ushort* __restrict__ Wt,
                                                  const float* __restrict__ bias,
                                                  const float* __restrict__ W2,
                                                  const float* __restrict__ b2,
                                                  void* __restrict__ C, int N) {
  __shared__ uint4 Al[128 * 16];
  __shared__ uint4 Wl[128 * 16];
  const int tid = threadIdx.x;
  const int wave = tid >> 6;
  const int lane = tid & 63;
  const int l16 = lane & 15;
  const int quad = lane >> 4;
  const int m0 = blockIdx.x * 128;

  f32x4 acc[8] = {};
  const int r_s = tid >> 4;
  const int j8 = tid & 15;
#pragma unroll
  for (int it = 0; it < 4; ++it) {
    int m = it * 32 + r_s;
    Al[m * 16 + (j8 ^ (m & 15))] = *(const uint4*)(A + (size_t)(m0 + m) * 128 + j8 * 8);
  }
#pragma unroll
  for (int it = 0; it < 4; ++it) {
    int n = it * 32 + r_s;
    Wl[n * 16 + (j8 ^ (n & 15))] = *(const uint4*)(Wt + (size_t)n * 128 + j8 * 8);
  }
  __syncthreads();
#pragma unroll
  for (int s = 0; s < 4; ++s) {
    const int j = s * 4 + quad;
    const int arow = wave * 16 + l16;
    bf16x8 a = *(const bf16x8*)&Al[arow * 16 + (j ^ (arow & 15))];
#pragma unroll
    for (int c = 0; c < 8; ++c) {
      const int brow = c * 16 + l16;
      bf16x8 b = *(const bf16x8*)&Wl[brow * 16 + (j ^ (brow & 15))];
      acc[c] = __builtin_amdgcn_mfma_f32_16x16x32_bf16(a, b, acc[c], 0, 0, 0);
    }
  }

  float bv[8];
#pragma unroll
  for (int c = 0; c < 8; ++c) bv[c] = bias[c * 16 + l16];

  if constexpr (MODE == 3) {
    float w20[8], w21[8];
#pragma unroll
    for (int c = 0; c < 8; ++c) {
      int colj = c * 16 + l16;
      w20[c] = W2[colj * 2 + 0];
      w21[c] = W2[colj * 2 + 1];
    }
    float bb0 = b2[0], bb1 = b2[1];
#pragma unroll
    for (int reg = 0; reg < 4; ++reg) {
      float o0 = 0.f, o1 = 0.f;
#pragma unroll
      for (int c = 0; c < 8; ++c) {
        float v = acc[c][reg] + bv[c];
        v = v >= 0.f ? v : 0.01f * v;
        o0 = fmaf(v, w20[c], o0);
        o1 = fmaf(v, w21[c], o1);
      }
      o0 += __shfl_xor(o0, 1); o0 += __shfl_xor(o0, 2);
      o0 += __shfl_xor(o0, 4); o0 += __shfl_xor(o0, 8);
      o1 += __shfl_xor(o1, 1); o1 += __shfl_xor(o1, 2);
      o1 += __shfl_xor(o1, 4); o1 += __shfl_xor(o1, 8);
      int row = m0 + wave * 16 + quad * 4 + reg;
      if (l16 == 0 && row < N)
        *(float2*)((float*)C + (size_t)row * 2) = make_float2(o0 + bb0, o1 + bb1);
    }
    return;
  }

#pragma unroll
  for (int reg = 0; reg < 4; ++reg) {
    int row = m0 + wave * 16 + quad * 4 + reg;
    if (row < N) {
#pragma unroll
      for (int c = 0; c < 8; ++c) {
        float v = acc[c][reg] + bv[c];
        __hip_bfloat16 h = __float2bfloat16(v);
        ((ushort*)C)[(size_t)row * 128 + c * 16 + l16] = *(ushort*)&h;
      }
    }
  }
}

// ---------------- CSR-pull aggregation, bf16 -> bf16 ----------------
// Edge loop unrolled 4 (+2 +1 tail) so each 16-lane group keeps up to
// 4 independent 256B row-gathers in flight (latency hiding).

__global__ __launch_bounds__(256) void agg_k(const ushort* __restrict__ T,
                                             const float* __restrict__ dinv,
                                             const int* __restrict__ rp,
                                             const int2* __restrict__ ew,
                                             ushort* __restrict__ O, int N) {
  int l = threadIdx.x & 15;
  int node = blockIdx.x * 16 + (threadIdx.x >> 4);
  if (node >= N) return;
  float di = dinv[node];
  float dsq = di * di;
  const uint4* T4 = (const uint4*)T;
  float a[8];
  {
    uint4 sv = T4[(size_t)node * 16 + l];
    uint u[4] = {sv.x, sv.y, sv.z, sv.w};
#pragma unroll
    for (int p = 0; p < 4; ++p) {
      a[2 * p + 0] = __uint_as_float(u[p] << 16) * dsq;
      a[2 * p + 1] = __uint_as_float(u[p] & 0xFFFF0000u) * dsq;
    }
  }
  int e = rp[node];
  const int e1 = rp[node + 1];
  for (; e + 4 <= e1; e += 4) {
    int2 p0 = ew[e + 0], p1 = ew[e + 1], p2 = ew[e + 2], p3 = ew[e + 3];
    uint4 v0 = T4[(size_t)p0.x * 16 + l];
    uint4 v1 = T4[(size_t)p1.x * 16 + l];
    uint4 v2 = T4[(size_t)p2.x * 16 + l];
    uint4 v3 = T4[(size_t)p3.x * 16 + l];
    float w0 = __int_as_float(p0.y), w1 = __int_as_float(p1.y);
    float w2 = __int_as_float(p2.y), w3 = __int_as_float(p3.y);
    uint u0[4] = {v0.x, v0.y, v0.z, v0.w};
    uint u1[4] = {v1.x, v1.y, v1.z, v1.w};
    uint u2[4] = {v2.x, v2.y, v2.z, v2.w};
    uint u3[4] = {v3.x, v3.y, v3.z, v3.w};
#pragma unroll
    for (int p = 0; p < 4; ++p) {
      a[2 * p + 0] = fmaf(__uint_as_float(u0[p] << 16), w0, a[2 * p + 0]);
      a[2 * p + 1] = fmaf(__uint_as_float(u0[p] & 0xFFFF0000u), w0, a[2 * p + 1]);
      a[2 * p + 0] = fmaf(__uint_as_float(u1[p] << 16), w1, a[2 * p + 0]);
      a[2 * p + 1] = fmaf(__uint_as_float(u1[p] & 0xFFFF0000u), w1, a[2 * p + 1]);
      a[2 * p + 0] = fmaf(__uint_as_float(u2[p] << 16), w2, a[2 * p + 0]);
      a[2 * p + 1] = fmaf(__uint_as_float(u2[p] & 0xFFFF0000u), w2, a[2 * p + 1]);
      a[2 * p + 0] = fmaf(__uint_as_float(u3[p] << 16), w3, a[2 * p + 0]);
      a[2 * p + 1] = fmaf(__uint_as_float(u3[p] & 0xFFFF0000u), w3, a[2 * p + 1]);
    }
  }
  if (e + 2 <= e1) {
    int2 p0 = ew[e + 0], p1 = ew[e + 1];
    uint4 v0 = T4[(size_t)p0.x * 16 + l];
    uint4 v1 = T4[(size_t)p1.x * 16 + l];
    float w0 = __int_as_float(p0.y), w1 = __int_as_float(p1.y);
    uint u0[4] = {v0.x, v0.y, v0.z, v0.w};
    uint u1[4] = {v1.x, v1.y, v1.z, v1.w};
#pragma unroll
    for (int p = 0; p < 4; ++p) {
      a[2 * p + 0] = fmaf(__uint_as_float(u0[p] << 16), w0, a[2 * p + 0]);
      a[2 * p + 1] = fmaf(__uint_as_float(u0[p] & 0xFFFF0000u), w0, a[2 * p + 1]);
      a[2 * p + 0] = fmaf(__uint_as_float(u1[p] << 16), w1, a[2 * p + 0]);
      a[2 * p + 1] = fmaf(__uint_as_float(u1[p] & 0xFFFF0000u), w1, a[2 * p + 1]);
    }
    e += 2;
  }
  if (e < e1) {
    int2 pw = ew[e];
    float w = __int_as_float(pw.y);
    uint4 v = T4[(size_t)pw.x * 16 + l];
    uint u[4] = {v.x, v.y, v.z, v.w};
#pragma unroll
    for (int p = 0; p < 4; ++p) {
      a[2 * p + 0] = fmaf(__uint_as_float(u[p] << 16), w, a[2 * p + 0]);
      a[2 * p + 1] = fmaf(__uint_as_float(u[p] & 0xFFFF0000u), w, a[2 * p + 1]);
    }
  }
  union { uint4 v; ushort s[8]; } uo;
#pragma unroll
  for (int j = 0; j < 8; ++j) {
    __hip_bfloat16 h = __float2bfloat16(a[j]);
    uo.s[j] = *(ushort*)&h;
  }
  ((uint4*)O)[(size_t)node * 16 + l] = uo.v;
}

// ---------------- launch ----------------

extern "C" void kernel_launch(void* const* d_in, const int* in_sizes, int n_in,
                              void* d_out, int out_size, void* d_ws, size_t ws_size,
                              hipStream_t stream) {
  const float* x = (const float*)d_in[0];
  const int* ei = (const int*)d_in[1];
  const float* W_in = (const float*)d_in[3];
  const float* b_in = (const float*)d_in[4];
  const float* W_g  = (const float*)d_in[5];
  const float* b_g  = (const float*)d_in[6];
  const float* W_o1 = (const float*)d_in[7];
  const float* b_o1 = (const float*)d_in[8];
  const float* W_o2 = (const float*)d_in[9];
  const float* b_o2 = (const float*)d_in[10];

  const int D = in_sizes[4];        // 128
  const int ND = in_sizes[3] / D;   // 239
  const int N = in_sizes[0] / ND;   // 100000
  const int E = in_sizes[2];        // 640000
  const int* src = ei;
  const int* dst = ei + E;

  const int N_pad = ((N + 127) / 128) * 128;
  const size_t np = (size_t)N_pad;
  const int KP1 = 256;

  ushort* xb = (ushort*)d_ws;                 // np*256 bf16 (rows >= N unwritten; outputs guarded)
  ushort* hA = xb + np * 256;                 // np*128 bf16
  ushort* hB = hA + np * 128;                 // np*128 bf16
  ushort* Wt_in = hB + np * 128;              // 128*256 bf16
  ushort* Wt_g  = Wt_in + 128 * 256;          // 128*128
  ushort* Wt_o1 = Wt_g + 128 * 128;           // 128*128
  float* dinv = (float*)(Wt_o1 + 128 * 128);  // N f32
  int* cnt  = (int*)(dinv + N);
  int* rp   = cnt + N;
  int* bsum = rp + (N + 1);
  int2* ew  = (int2*)(((size_t)(bsum + 1024) + 7) & ~(size_t)7);

  const int NB = (N + 1023) / 1024;

  wtr_all_k<<<(128 * KP1 + 2 * 128 * 128 + 255) / 256, 256, 0, stream>>>(
      W_in, W_g, W_o1, Wt_in, Wt_g, Wt_o1, ND);

  int cblocks = (N * 32 + 255) / 256;
  if (cblocks > 2048) cblocks = 2048;
  cvt_k<<<cblocks, 256, 0, stream>>>(x, xb, N, ND);

  zero_k<<<(N + 255) / 256, 256, 0, stream>>>(cnt, N);
  hist_k<<<(E + 255) / 256, 256, 0, stream>>>(dst, cnt, E);
  scan1_k<<<NB, 256, 0, stream>>>(cnt, rp, bsum, N);
  scan2_k<<<1, 256, 0, stream>>>(bsum, NB);
  scan3_k<<<(N + 255) / 256, 256, 0, stream>>>(rp, cnt /*pos*/, bsum, dinv, N, E);
  fill_k<<<(E + 255) / 256, 256, 0, stream>>>(src, dst, dinv, cnt, ew, E);

  const int gblocks = N_pad / 128;
  const int ablocks = (N + 15) / 16;
  gemm1b_k<<<gblocks, 512, 0, stream>>>(xb, Wt_in, b_in, hA, N);
  agg_k<<<ablocks, 256, 0, stream>>>(hA, dinv, rp, ew, hB, N);
  mgemm_k<1><<<gblocks, 512, 0, stream>>>(hB, Wt_g, b_g, nullptr, nullptr, hA, N);
  agg_k<<<ablocks, 256, 0, stream>>>(hA, dinv, rp, ew, hB, N);
  mgemm_k<1><<<gblocks, 512, 0, stream>>>(hB, Wt_g, b_g, nullptr, nullptr, hA, N);
  mgemm_k<3><<<gblocks, 512, 0, stream>>>(hA, Wt_o1, b_o1, W_o2, b_o2, d_out, N);
}

// Round 9
// 353.300 us; speedup vs baseline: 1.0269x; 1.0211x over previous
//
#include <hip/hip_runtime.h>
#include <hip/hip_bf16.h>

// GCN pipeline on MI355X — MFMA bf16 GEMMs, fp32 accumulate, bf16 dataflow.
// R16 (= R15 resubmit; round 8 was an infra container failure, not a kernel
//      failure — same as round 1, which passed on resubmission).
//      Base: best-known-good R9 (347.4us, passed). Two contained additions:
//      1. cnt zeroing merged into wtr_all_k (independent segment, -1 dispatch)
//      2. agg_k edge loop deepened to 8+4+2+1 (8 gathers in flight)
//      Everything else byte-identical to R9.

typedef __attribute__((ext_vector_type(8))) __bf16 bf16x8;
typedef __attribute__((ext_vector_type(4))) float f32x4;

typedef __attribute__((address_space(1))) const void gvoid_t;
typedef __attribute__((address_space(3))) void svoid_t;

// All 3 weight transposes + cnt zeroing in one dispatch.
// seg0 [0, 32768):        W_in [ND][128] -> Wt_in [128][256] (zero pad k>=ND)
// seg1 [32768, 49152):    W_g  [128][128] -> Wt_g  [128][128]
// seg2 [49152, 65536):    W_o1 [128][128] -> Wt_o1 [128][128]
// seg3 [65536, 65536+N):  cnt[i] = 0
__global__ __launch_bounds__(256) void wtr_all_k(const float* __restrict__ W_in,
                                                 const float* __restrict__ W_g,
                                                 const float* __restrict__ W_o1,
                                                 ushort* __restrict__ Wt_in,
                                                 ushort* __restrict__ Wt_g,
                                                 ushort* __restrict__ Wt_o1,
                                                 int* __restrict__ cnt, int N, int ND) {
  int idx = blockIdx.x * 256 + threadIdx.x;
  if (idx < 128 * 256) {
    int n = idx >> 8, k = idx & 255;
    float v = (k < ND) ? W_in[(size_t)k * 128 + n] : 0.f;
    __hip_bfloat16 h = __float2bfloat16(v);
    Wt_in[idx] = *(ushort*)&h;
  } else if (idx < 128 * 256 + 128 * 128) {
    int j = idx - 128 * 256;
    int n = j >> 7, k = j & 127;
    __hip_bfloat16 h = __float2bfloat16(W_g[(size_t)k * 128 + n]);
    Wt_g[j] = *(ushort*)&h;
  } else if (idx < 128 * 256 + 2 * 128 * 128) {
    int j = idx - 128 * 256 - 128 * 128;
    int n = j >> 7, k = j & 127;
    __hip_bfloat16 h = __float2bfloat16(W_o1[(size_t)k * 128 + n]);
    Wt_o1[j] = *(ushort*)&h;
  } else {
    int i = idx - 65536;
    if (i < N) cnt[i] = 0;
  }
}

// ---------------- CSR build ----------------

__global__ __launch_bounds__(256) void hist_k(const int* __restrict__ dst, int* __restrict__ cnt, int E) {
  int e = blockIdx.x * 256 + threadIdx.x;
  if (e < E) atomicAdd(&cnt[dst[e]], 1);
}

__global__ __launch_bounds__(256) void scan1_k(const int* __restrict__ cnt, int* __restrict__ rp,
                                               int* __restrict__ bsum, int N) {
  __shared__ int sd[256];
  int t = threadIdx.x;
  int base = blockIdx.x * 1024 + t * 4;
  int v0 = (base + 0 < N) ? cnt[base + 0] : 0;
  int v1 = (base + 1 < N) ? cnt[base + 1] : 0;
  int v2 = (base + 2 < N) ? cnt[base + 2] : 0;
  int v3 = (base + 3 < N) ? cnt[base + 3] : 0;
  int ts = v0 + v1 + v2 + v3;
  sd[t] = ts;
  __syncthreads();
  for (int off = 1; off < 256; off <<= 1) {
    int y = (t >= off) ? sd[t - off] : 0;
    __syncthreads();
    sd[t] += y;
    __syncthreads();
  }
  int x = sd[t] - ts;
  if (t == 255) bsum[blockIdx.x] = sd[255];
  if (base + 0 < N) rp[base + 0] = x; x += v0;
  if (base + 1 < N) rp[base + 1] = x; x += v1;
  if (base + 2 < N) rp[base + 2] = x; x += v2;
  if (base + 3 < N) rp[base + 3] = x;
}

__global__ __launch_bounds__(256) void scan2_k(int* __restrict__ bsum, int NB) {
  __shared__ int sd[256];
  int t = threadIdx.x;
  int base = t * 4;
  int v0 = (base + 0 < NB) ? bsum[base + 0] : 0;
  int v1 = (base + 1 < NB) ? bsum[base + 1] : 0;
  int v2 = (base + 2 < NB) ? bsum[base + 2] : 0;
  int v3 = (base + 3 < NB) ? bsum[base + 3] : 0;
  int ts = v0 + v1 + v2 + v3;
  sd[t] = ts;
  __syncthreads();
  for (int off = 1; off < 256; off <<= 1) {
    int y = (t >= off) ? sd[t - off] : 0;
    __syncthreads();
    sd[t] += y;
    __syncthreads();
  }
  int x = sd[t] - ts;
  if (base + 0 < NB) bsum[base + 0] = x; x += v0;
  if (base + 1 < NB) bsum[base + 1] = x; x += v1;
  if (base + 2 < NB) bsum[base + 2] = x; x += v2;
  if (base + 3 < NB) bsum[base + 3] = x;
}

__global__ __launch_bounds__(256) void scan3_k(int* __restrict__ rp, int* __restrict__ pos,
                                               const int* __restrict__ bsum,
                                               float* __restrict__ dinv, int N, int E) {
  int i = blockIdx.x * 256 + threadIdx.x;
  if (i < N) {
    int c = pos[i];  // pos aliases cnt: still the original count here
    int v = rp[i] + bsum[i >> 10];
    dinv[i] = rsqrtf((float)c + 1.0f);
    rp[i] = v;
    pos[i] = v;
  }
  if (i == 0) rp[N] = E;
}

__global__ __launch_bounds__(256) void fill_k(const int* __restrict__ src, const int* __restrict__ dst,
                                              const float* __restrict__ dinv,
                                              int* __restrict__ pos, int2* __restrict__ ew, int E) {
  int e = blockIdx.x * 256 + threadIdx.x;
  if (e < E) {
    int d = dst[e];
    int s = src[e];
    int idx = atomicAdd(&pos[d], 1);
    ew[idx] = make_int2(s, __float_as_int(dinv[s] * dinv[d]));
  }
}

// ---------------- GEMM1: hA = leaky(x[N,239] @ Wt^T + bias), bf16 out ----------------
// A tile = 64 rows x 239 f32, staged FLAT into LDS by global_load_lds DMA (layout is
// the exact global image, stride 239 f32 = 956B). bf16 conversion happens at
// fragment-read time. Wl chunked 128x72. (byte-identical to R9)

__global__ __launch_bounds__(512, 4) void gemm1_k(const float* __restrict__ x,
                                                  const ushort* __restrict__ Wt,
                                                  const float* __restrict__ bias,
                                                  ushort* __restrict__ C, int N, int Ka) {
  __shared__ float Af[64 * 239 + 8];   // 61,216 B (flat f32 image of the x tile)
  __shared__ ushort Wl[128 * 72];      // 18,432 B
  const int tid = threadIdx.x;
  const int wave = tid >> 6;
  const int lane = tid & 63;
  const int l16 = lane & 15;
  const int quad = lane >> 4;
  const int m0 = blockIdx.x * 64;

  // ---- A staging: pure DMA of min(64, N-m0)*Ka floats (contiguous region) ----
  {
    int rows = N - m0;
    if (rows > 64) rows = 64;
    const int nwords = rows * Ka;                // f32 words
    const float* __restrict__ gsrc = x + (size_t)m0 * Ka;
    const int nchunks = nwords >> 8;             // 256 words = 1KB per wave-issue
    for (int ch = wave; ch < nchunks; ch += 8) {
      __builtin_amdgcn_global_load_lds(
          (gvoid_t*)(gsrc + ch * 256 + lane * 4),
          (svoid_t*)(&Af[ch * 256]), 16, 0, 0);
    }
    // tail (< 256 words): guarded per-lane word copy
    for (int i = (nchunks << 8) + tid; i < nwords; i += 512) {
      Af[i] = gsrc[i];
    }
  }

  f32x4 acc[4] = {};
  const int wr = wave >> 1;   // row group 0..3 (16 rows each)
  const int wc = wave & 1;    // col half 0..1 (64 cols each)
  const int wn = tid >> 2;
  const int wseg = tid & 3;
#pragma unroll
  for (int kc = 0; kc < 4; ++kc) {
    __syncthreads();  // (kc==0: also drains the A DMA via compiler vmcnt(0))
    *(uint4*)&Wl[wn * 72 + wseg * 16] =
        *(const uint4*)(Wt + (size_t)wn * 256 + kc * 64 + wseg * 16);
    *(uint4*)&Wl[wn * 72 + wseg * 16 + 8] =
        *(const uint4*)(Wt + (size_t)wn * 256 + kc * 64 + wseg * 16 + 8);
    __syncthreads();
#pragma unroll
    for (int s = 0; s < 2; ++s) {
      const int koff = kc * 64 + s * 32 + quad * 8;
      bf16x8 a = {};
      const float* ap = &Af[(wr * 16 + l16) * Ka + koff];
      if (koff + 8 <= Ka) {
#pragma unroll
        for (int j = 0; j < 8; ++j) {
          __hip_bfloat16 h = __float2bfloat16(ap[j]);
          a[j] = *(__bf16*)&h;
        }
      } else if (koff < Ka) {
#pragma unroll
        for (int j = 0; j < 8; ++j) {
          if (koff + j < Ka) {
            __hip_bfloat16 h = __float2bfloat16(ap[j]);
            a[j] = *(__bf16*)&h;
          }
        }
      }
      const int wof = s * 32 + quad * 8;
#pragma unroll
      for (int c = 0; c < 4; ++c) {
        bf16x8 b = *(const bf16x8*)&Wl[(wc * 64 + c * 16 + l16) * 72 + wof];
        acc[c] = __builtin_amdgcn_mfma_f32_16x16x32_bf16(a, b, acc[c], 0, 0, 0);
      }
    }
  }

  float bv[4];
#pragma unroll
  for (int c = 0; c < 4; ++c) bv[c] = bias[wc * 64 + c * 16 + l16];
#pragma unroll
  for (int reg = 0; reg < 4; ++reg) {
    int row = m0 + wr * 16 + quad * 4 + reg;
    if (row < N) {
#pragma unroll
      for (int c = 0; c < 4; ++c) {
        float v = acc[c][reg] + bv[c];
        v = v >= 0.f ? v : 0.01f * v;
        __hip_bfloat16 h = __float2bfloat16(v);
        C[(size_t)row * 128 + wc * 64 + c * 16 + l16] = *(ushort*)&h;
      }
    }
  }
}

// ---------------- MFMA GEMM (bf16 A, K=128): C = A @ Wt^T ----------------
// MODE: 1 = bf16 + bias; 3 = fused leaky(.+bias)@W2 + b2 -> out[N,2] f32.
// (byte-identical to R9)

template <int MODE>
__global__ __launch_bounds__(512, 4) void mgemm_k(const ushort* __restrict__ A,
                                                  const ushort* __restrict__ Wt,
                                                  const float* __restrict__ bias,
                                                  const float* __restrict__ W2,
                                                  const float* __restrict__ b2,
                                                  void* __restrict__ C, int N) {
  __shared__ uint4 Al[128 * 16];
  __shared__ uint4 Wl[128 * 16];
  const int tid = threadIdx.x;
  const int wave = tid >> 6;
  const int lane = tid & 63;
  const int l16 = lane & 15;
  const int quad = lane >> 4;
  const int m0 = blockIdx.x * 128;

  f32x4 acc[8] = {};
  const int r_s = tid >> 4;
  const int j8 = tid & 15;
#pragma unroll
  for (int it = 0; it < 4; ++it) {
    int m = it * 32 + r_s;
    Al[m * 16 + (j8 ^ (m & 15))] = *(const uint4*)(A + (size_t)(m0 + m) * 128 + j8 * 8);
  }
#pragma unroll
  for (int it = 0; it < 4; ++it) {
    int n = it * 32 + r_s;
    Wl[n * 16 + (j8 ^ (n & 15))] = *(const uint4*)(Wt + (size_t)n * 128 + j8 * 8);
  }
  __syncthreads();
#pragma unroll
  for (int s = 0; s < 4; ++s) {
    const int j = s * 4 + quad;
    const int arow = wave * 16 + l16;
    bf16x8 a = *(const bf16x8*)&Al[arow * 16 + (j ^ (arow & 15))];
#pragma unroll
    for (int c = 0; c < 8; ++c) {
      const int brow = c * 16 + l16;
      bf16x8 b = *(const bf16x8*)&Wl[brow * 16 + (j ^ (brow & 15))];
      acc[c] = __builtin_amdgcn_mfma_f32_16x16x32_bf16(a, b, acc[c], 0, 0, 0);
    }
  }

  float bv[8];
#pragma unroll
  for (int c = 0; c < 8; ++c) bv[c] = bias[c * 16 + l16];

  if constexpr (MODE == 3) {
    float w20[8], w21[8];
#pragma unroll
    for (int c = 0; c < 8; ++c) {
      int colj = c * 16 + l16;
      w20[c] = W2[colj * 2 + 0];
      w21[c] = W2[colj * 2 + 1];
    }
    float bb0 = b2[0], bb1 = b2[1];
#pragma unroll
    for (int reg = 0; reg < 4; ++reg) {
      float o0 = 0.f, o1 = 0.f;
#pragma unroll
      for (int c = 0; c < 8; ++c) {
        float v = acc[c][reg] + bv[c];
        v = v >= 0.f ? v : 0.01f * v;
        o0 = fmaf(v, w20[c], o0);
        o1 = fmaf(v, w21[c], o1);
      }
      o0 += __shfl_xor(o0, 1); o0 += __shfl_xor(o0, 2);
      o0 += __shfl_xor(o0, 4); o0 += __shfl_xor(o0, 8);
      o1 += __shfl_xor(o1, 1); o1 += __shfl_xor(o1, 2);
      o1 += __shfl_xor(o1, 4); o1 += __shfl_xor(o1, 8);
      int row = m0 + wave * 16 + quad * 4 + reg;
      if (l16 == 0 && row < N)
        *(float2*)((float*)C + (size_t)row * 2) = make_float2(o0 + bb0, o1 + bb1);
    }
    return;
  }

#pragma unroll
  for (int reg = 0; reg < 4; ++reg) {
    int row = m0 + wave * 16 + quad * 4 + reg;
    if (row < N) {
#pragma unroll
      for (int c = 0; c < 8; ++c) {
        float v = acc[c][reg] + bv[c];
        __hip_bfloat16 h = __float2bfloat16(v);
        ((ushort*)C)[(size_t)row * 128 + c * 16 + l16] = *(ushort*)&h;
      }
    }
  }
}

// ---------------- CSR-pull aggregation, bf16 -> bf16 ----------------
// Edge loop 8+4+2+1 — up to 8 independent 256B row-gathers in flight
// per 16-lane group.

__global__ __launch_bounds__(256) void agg_k(const ushort* __restrict__ T,
                                             const float* __restrict__ dinv,
                                             const int* __restrict__ rp,
                                             const int2* __restrict__ ew,
                                             ushort* __restrict__ O, int N) {
  int l = threadIdx.x & 15;
  int node = blockIdx.x * 16 + (threadIdx.x >> 4);
  if (node >= N) return;
  float di = dinv[node];
  float dsq = di * di;
  const uint4* T4 = (const uint4*)T;
  float a[8];
  {
    uint4 sv = T4[(size_t)node * 16 + l];
    uint u[4] = {sv.x, sv.y, sv.z, sv.w};
#pragma unroll
    for (int p = 0; p < 4; ++p) {
      a[2 * p + 0] = __uint_as_float(u[p] << 16) * dsq;
      a[2 * p + 1] = __uint_as_float(u[p] & 0xFFFF0000u) * dsq;
    }
  }
  int e = rp[node];
  const int e1 = rp[node + 1];
  for (; e + 8 <= e1; e += 8) {
    int2 q0 = ew[e + 0], q1 = ew[e + 1], q2 = ew[e + 2], q3 = ew[e + 3];
    int2 q4 = ew[e + 4], q5 = ew[e + 5], q6 = ew[e + 6], q7 = ew[e + 7];
    uint4 x0 = T4[(size_t)q0.x * 16 + l];
    uint4 x1 = T4[(size_t)q1.x * 16 + l];
    uint4 x2 = T4[(size_t)q2.x * 16 + l];
    uint4 x3 = T4[(size_t)q3.x * 16 + l];
    uint4 x4 = T4[(size_t)q4.x * 16 + l];
    uint4 x5 = T4[(size_t)q5.x * 16 + l];
    uint4 x6 = T4[(size_t)q6.x * 16 + l];
    uint4 x7 = T4[(size_t)q7.x * 16 + l];
    uint g0[4] = {x0.x, x0.y, x0.z, x0.w};
    uint g1[4] = {x1.x, x1.y, x1.z, x1.w};
    uint g2[4] = {x2.x, x2.y, x2.z, x2.w};
    uint g3[4] = {x3.x, x3.y, x3.z, x3.w};
    uint g4[4] = {x4.x, x4.y, x4.z, x4.w};
    uint g5[4] = {x5.x, x5.y, x5.z, x5.w};
    uint g6[4] = {x6.x, x6.y, x6.z, x6.w};
    uint g7[4] = {x7.x, x7.y, x7.z, x7.w};
    float y0 = __int_as_float(q0.y), y1 = __int_as_float(q1.y);
    float y2 = __int_as_float(q2.y), y3 = __int_as_float(q3.y);
    float y4 = __int_as_float(q4.y), y5 = __int_as_float(q5.y);
    float y6 = __int_as_float(q6.y), y7 = __int_as_float(q7.y);
#pragma unroll
    for (int p = 0; p < 4; ++p) {
      a[2 * p + 0] = fmaf(__uint_as_float(g0[p] << 16), y0, a[2 * p + 0]);
      a[2 * p + 1] = fmaf(__uint_as_float(g0[p] & 0xFFFF0000u), y0, a[2 * p + 1]);
      a[2 * p + 0] = fmaf(__uint_as_float(g1[p] << 16), y1, a[2 * p + 0]);
      a[2 * p + 1] = fmaf(__uint_as_float(g1[p] & 0xFFFF0000u), y1, a[2 * p + 1]);
      a[2 * p + 0] = fmaf(__uint_as_float(g2[p] << 16), y2, a[2 * p + 0]);
      a[2 * p + 1] = fmaf(__uint_as_float(g2[p] & 0xFFFF0000u), y2, a[2 * p + 1]);
      a[2 * p + 0] = fmaf(__uint_as_float(g3[p] << 16), y3, a[2 * p + 0]);
      a[2 * p + 1] = fmaf(__uint_as_float(g3[p] & 0xFFFF0000u), y3, a[2 * p + 1]);
      a[2 * p + 0] = fmaf(__uint_as_float(g4[p] << 16), y4, a[2 * p + 0]);
      a[2 * p + 1] = fmaf(__uint_as_float(g4[p] & 0xFFFF0000u), y4, a[2 * p + 1]);
      a[2 * p + 0] = fmaf(__uint_as_float(g5[p] << 16), y5, a[2 * p + 0]);
      a[2 * p + 1] = fmaf(__uint_as_float(g5[p] & 0xFFFF0000u), y5, a[2 * p + 1]);
      a[2 * p + 0] = fmaf(__uint_as_float(g6[p] << 16), y6, a[2 * p + 0]);
      a[2 * p + 1] = fmaf(__uint_as_float(g6[p] & 0xFFFF0000u), y6, a[2 * p + 1]);
      a[2 * p + 0] = fmaf(__uint_as_float(g7[p] << 16), y7, a[2 * p + 0]);
      a[2 * p + 1] = fmaf(__uint_as_float(g7[p] & 0xFFFF0000u), y7, a[2 * p + 1]);
    }
  }
  if (e + 4 <= e1) {
    int2 p0 = ew[e + 0], p1 = ew[e + 1], p2 = ew[e + 2], p3 = ew[e + 3];
    uint4 v0 = T4[(size_t)p0.x * 16 + l];
    uint4 v1 = T4[(size_t)p1.x * 16 + l];
    uint4 v2 = T4[(size_t)p2.x * 16 + l];
    uint4 v3 = T4[(size_t)p3.x * 16 + l];
    float w0 = __int_as_float(p0.y), w1 = __int_as_float(p1.y);
    float w2 = __int_as_float(p2.y), w3 = __int_as_float(p3.y);
    uint u0[4] = {v0.x, v0.y, v0.z, v0.w};
    uint u1[4] = {v1.x, v1.y, v1.z, v1.w};
    uint u2[4] = {v2.x, v2.y, v2.z, v2.w};
    uint u3[4] = {v3.x, v3.y, v3.z, v3.w};
#pragma unroll
    for (int p = 0; p < 4; ++p) {
      a[2 * p + 0] = fmaf(__uint_as_float(u0[p] << 16), w0, a[2 * p + 0]);
      a[2 * p + 1] = fmaf(__uint_as_float(u0[p] & 0xFFFF0000u), w0, a[2 * p + 1]);
      a[2 * p + 0] = fmaf(__uint_as_float(u1[p] << 16), w1, a[2 * p + 0]);
      a[2 * p + 1] = fmaf(__uint_as_float(u1[p] & 0xFFFF0000u), w1, a[2 * p + 1]);
      a[2 * p + 0] = fmaf(__uint_as_float(u2[p] << 16), w2, a[2 * p + 0]);
      a[2 * p + 1] = fmaf(__uint_as_float(u2[p] & 0xFFFF0000u), w2, a[2 * p + 1]);
      a[2 * p + 0] = fmaf(__uint_as_float(u3[p] << 16), w3, a[2 * p + 0]);
      a[2 * p + 1] = fmaf(__uint_as_float(u3[p] & 0xFFFF0000u), w3, a[2 * p + 1]);
    }
    e += 4;
  }
  if (e + 2 <= e1) {
    int2 p0 = ew[e + 0], p1 = ew[e + 1];
    uint4 v0 = T4[(size_t)p0.x * 16 + l];
    uint4 v1 = T4[(size_t)p1.x * 16 + l];
    float w0 = __int_as_float(p0.y), w1 = __int_as_float(p1.y);
    uint u0[4] = {v0.x, v0.y, v0.z, v0.w};
    uint u1[4] = {v1.x, v1.y, v1.z, v1.w};
#pragma unroll
    for (int p = 0; p < 4; ++p) {
      a[2 * p + 0] = fmaf(__uint_as_float(u0[p] << 16), w0, a[2 * p + 0]);
      a[2 * p + 1] = fmaf(__uint_as_float(u0[p] & 0xFFFF0000u), w0, a[2 * p + 1]);
      a[2 * p + 0] = fmaf(__uint_as_float(u1[p] << 16), w1, a[2 * p + 0]);
      a[2 * p + 1] = fmaf(__uint_as_float(u1[p] & 0xFFFF0000u), w1, a[2 * p + 1]);
    }
    e += 2;
  }
  if (e < e1) {
    int2 pw = ew[e];
    float w = __int_as_float(pw.y);
    uint4 v = T4[(size_t)pw.x * 16 + l];
    uint u[4] = {v.x, v.y, v.z, v.w};
#pragma unroll
    for (int p = 0; p < 4; ++p) {
      a[2 * p + 0] = fmaf(__uint_as_float(u[p] << 16), w, a[2 * p + 0]);
      a[2 * p + 1] = fmaf(__uint_as_float(u[p] & 0xFFFF0000u), w, a[2 * p + 1]);
    }
  }
  union { uint4 v; ushort s[8]; } uo;
#pragma unroll
  for (int j = 0; j < 8; ++j) {
    __hip_bfloat16 h = __float2bfloat16(a[j]);
    uo.s[j] = *(ushort*)&h;
  }
  ((uint4*)O)[(size_t)node * 16 + l] = uo.v;
}

// ---------------- launch ----------------

extern "C" void kernel_launch(void* const* d_in, const int* in_sizes, int n_in,
                              void* d_out, int out_size, void* d_ws, size_t ws_size,
                              hipStream_t stream) {
  const float* x = (const float*)d_in[0];
  const int* ei = (const int*)d_in[1];
  const float* W_in = (const float*)d_in[3];
  const float* b_in = (const float*)d_in[4];
  const float* W_g  = (const float*)d_in[5];
  const float* b_g  = (const float*)d_in[6];
  const float* W_o1 = (const float*)d_in[7];
  const float* b_o1 = (const float*)d_in[8];
  const float* W_o2 = (const float*)d_in[9];
  const float* b_o2 = (const float*)d_in[10];

  const int D = in_sizes[4];        // 128
  const int ND = in_sizes[3] / D;   // 239
  const int N = in_sizes[0] / ND;   // 100000
  const int E = in_sizes[2];        // 640000
  const int* src = ei;
  const int* dst = ei + E;

  const int N_pad = ((N + 127) / 128) * 128;
  const size_t np = (size_t)N_pad;

  ushort* hA = (ushort*)d_ws;                 // np*128 bf16
  ushort* hB = hA + np * 128;                 // np*128 bf16
  ushort* Wt_in = hB + np * 128;              // 128*256 bf16
  ushort* Wt_g  = Wt_in + 128 * 256;          // 128*128
  ushort* Wt_o1 = Wt_g + 128 * 128;           // 128*128
  float* dinv = (float*)(Wt_o1 + 128 * 128);  // N f32
  int* cnt  = (int*)(dinv + N);
  int* rp   = cnt + N;
  int* bsum = rp + (N + 1);
  int2* ew  = (int2*)(((size_t)(bsum + 1024) + 7) & ~(size_t)7);

  const int NB = (N + 1023) / 1024;

  wtr_all_k<<<(65536 + N + 255) / 256, 256, 0, stream>>>(
      W_in, W_g, W_o1, Wt_in, Wt_g, Wt_o1, cnt, N, ND);

  hist_k<<<(E + 255) / 256, 256, 0, stream>>>(dst, cnt, E);
  scan1_k<<<NB, 256, 0, stream>>>(cnt, rp, bsum, N);
  scan2_k<<<1, 256, 0, stream>>>(bsum, NB);
  scan3_k<<<(N + 255) / 256, 256, 0, stream>>>(rp, cnt /*pos*/, bsum, dinv, N, E);
  fill_k<<<(E + 255) / 256, 256, 0, stream>>>(src, dst, dinv, cnt, ew, E);

  const int g1blocks = (N + 63) / 64;
  const int gblocks = N_pad / 128;
  const int ablocks = (N + 15) / 16;
  gemm1_k<<<g1blocks, 512, 0, stream>>>(x, Wt_in, b_in, hA, N, ND);
  agg_k<<<ablocks, 256, 0, stream>>>(hA, dinv, rp, ew, hB, N);
  mgemm_k<1><<<gblocks, 512, 0, stream>>>(hB, Wt_g, b_g, nullptr, nullptr, hA, N);
  agg_k<<<ablocks, 256, 0, stream>>>(hA, dinv, rp, ew, hB, N);
  mgemm_k<1><<<gblocks, 512, 0, stream>>>(hB, Wt_g, b_g, nullptr, nullptr, hA, N);
  mgemm_k<3><<<gblocks, 512, 0, stream>>>(hA, Wt_o1, b_o1, W_o2, b_o2, d_out, N);
}

// Round 10
// 336.270 us; speedup vs baseline: 1.0789x; 1.0506x over previous
//
#include <hip/hip_runtime.h>
#include <hip/hip_bf16.h>

// GCN pipeline on MI355X — MFMA bf16 GEMMs, fp32 accumulate, bf16 dataflow.
// R17: base R9 (347.4us best-known-good) + two independent-work fusions:
//      1. cnt zeroing merged into wtr_all_k (R16-proven, -1 dispatch)
//      2. hist fused into gemm1's dispatch as extra blocks (no data dep:
//         hist touches cnt only, gemm1 touches Wt_in/x/hA only; hist's
//         scatter-atomics hide under gemm1's idle pipes). -1 dispatch.
//      agg_k REVERTED to R9's 4+2+1 unroll (R16's unroll-8 was the only
//      mechanism-bearing suspect for the 347->353 drift: +48 live VGPRs).
//      11 dispatches total (R9 had 13).

typedef __attribute__((ext_vector_type(8))) __bf16 bf16x8;
typedef __attribute__((ext_vector_type(4))) float f32x4;

typedef __attribute__((address_space(1))) const void gvoid_t;
typedef __attribute__((address_space(3))) void svoid_t;

// All 3 weight transposes + cnt zeroing in one dispatch.
// seg0 [0, 32768):        W_in [ND][128] -> Wt_in [128][256] (zero pad k>=ND)
// seg1 [32768, 49152):    W_g  [128][128] -> Wt_g  [128][128]
// seg2 [49152, 65536):    W_o1 [128][128] -> Wt_o1 [128][128]
// seg3 [65536, 65536+N):  cnt[i] = 0
__global__ __launch_bounds__(256) void wtr_all_k(const float* __restrict__ W_in,
                                                 const float* __restrict__ W_g,
                                                 const float* __restrict__ W_o1,
                                                 ushort* __restrict__ Wt_in,
                                                 ushort* __restrict__ Wt_g,
                                                 ushort* __restrict__ Wt_o1,
                                                 int* __restrict__ cnt, int N, int ND) {
  int idx = blockIdx.x * 256 + threadIdx.x;
  if (idx < 128 * 256) {
    int n = idx >> 8, k = idx & 255;
    float v = (k < ND) ? W_in[(size_t)k * 128 + n] : 0.f;
    __hip_bfloat16 h = __float2bfloat16(v);
    Wt_in[idx] = *(ushort*)&h;
  } else if (idx < 128 * 256 + 128 * 128) {
    int j = idx - 128 * 256;
    int n = j >> 7, k = j & 127;
    __hip_bfloat16 h = __float2bfloat16(W_g[(size_t)k * 128 + n]);
    Wt_g[j] = *(ushort*)&h;
  } else if (idx < 128 * 256 + 2 * 128 * 128) {
    int j = idx - 128 * 256 - 128 * 128;
    int n = j >> 7, k = j & 127;
    __hip_bfloat16 h = __float2bfloat16(W_o1[(size_t)k * 128 + n]);
    Wt_o1[j] = *(ushort*)&h;
  } else {
    int i = idx - 65536;
    if (i < N) cnt[i] = 0;
  }
}

// ---------------- CSR build ----------------

__global__ __launch_bounds__(256) void scan1_k(const int* __restrict__ cnt, int* __restrict__ rp,
                                               int* __restrict__ bsum, int N) {
  __shared__ int sd[256];
  int t = threadIdx.x;
  int base = blockIdx.x * 1024 + t * 4;
  int v0 = (base + 0 < N) ? cnt[base + 0] : 0;
  int v1 = (base + 1 < N) ? cnt[base + 1] : 0;
  int v2 = (base + 2 < N) ? cnt[base + 2] : 0;
  int v3 = (base + 3 < N) ? cnt[base + 3] : 0;
  int ts = v0 + v1 + v2 + v3;
  sd[t] = ts;
  __syncthreads();
  for (int off = 1; off < 256; off <<= 1) {
    int y = (t >= off) ? sd[t - off] : 0;
    __syncthreads();
    sd[t] += y;
    __syncthreads();
  }
  int x = sd[t] - ts;
  if (t == 255) bsum[blockIdx.x] = sd[255];
  if (base + 0 < N) rp[base + 0] = x; x += v0;
  if (base + 1 < N) rp[base + 1] = x; x += v1;
  if (base + 2 < N) rp[base + 2] = x; x += v2;
  if (base + 3 < N) rp[base + 3] = x;
}

__global__ __launch_bounds__(256) void scan2_k(int* __restrict__ bsum, int NB) {
  __shared__ int sd[256];
  int t = threadIdx.x;
  int base = t * 4;
  int v0 = (base + 0 < NB) ? bsum[base + 0] : 0;
  int v1 = (base + 1 < NB) ? bsum[base + 1] : 0;
  int v2 = (base + 2 < NB) ? bsum[base + 2] : 0;
  int v3 = (base + 3 < NB) ? bsum[base + 3] : 0;
  int ts = v0 + v1 + v2 + v3;
  sd[t] = ts;
  __syncthreads();
  for (int off = 1; off < 256; off <<= 1) {
    int y = (t >= off) ? sd[t - off] : 0;
    __syncthreads();
    sd[t] += y;
    __syncthreads();
  }
  int x = sd[t] - ts;
  if (base + 0 < NB) bsum[base + 0] = x; x += v0;
  if (base + 1 < NB) bsum[base + 1] = x; x += v1;
  if (base + 2 < NB) bsum[base + 2] = x; x += v2;
  if (base + 3 < NB) bsum[base + 3] = x;
}

__global__ __launch_bounds__(256) void scan3_k(int* __restrict__ rp, int* __restrict__ pos,
                                               const int* __restrict__ bsum,
                                               float* __restrict__ dinv, int N, int E) {
  int i = blockIdx.x * 256 + threadIdx.x;
  if (i < N) {
    int c = pos[i];  // pos aliases cnt: still the original count here
    int v = rp[i] + bsum[i >> 10];
    dinv[i] = rsqrtf((float)c + 1.0f);
    rp[i] = v;
    pos[i] = v;
  }
  if (i == 0) rp[N] = E;
}

__global__ __launch_bounds__(256) void fill_k(const int* __restrict__ src, const int* __restrict__ dst,
                                              const float* __restrict__ dinv,
                                              int* __restrict__ pos, int2* __restrict__ ew, int E) {
  int e = blockIdx.x * 256 + threadIdx.x;
  if (e < E) {
    int d = dst[e];
    int s = src[e];
    int idx = atomicAdd(&pos[d], 1);
    ew[idx] = make_int2(s, __float_as_int(dinv[s] * dinv[d]));
  }
}

// ---------------- GEMM1 (+ fused hist): blocks [0, g1b) do the MFMA GEMM,
// blocks [g1b, g1b + ceil(E/512)) do the degree histogram (independent work,
// rides under gemm1's idle pipes). GEMM body byte-identical to R9. ----------

__global__ __launch_bounds__(512, 4) void gemm1h_k(const float* __restrict__ x,
                                                   const ushort* __restrict__ Wt,
                                                   const float* __restrict__ bias,
                                                   ushort* __restrict__ C, int N, int Ka,
                                                   int g1b,
                                                   const int* __restrict__ dst,
                                                   int* __restrict__ cnt, int E) {
  __shared__ float Af[64 * 239 + 8];   // 61,216 B (flat f32 image of the x tile)
  __shared__ ushort Wl[128 * 72];      // 18,432 B
  const int tid = threadIdx.x;

  if (blockIdx.x >= g1b) {
    // hist segment: no barriers, no LDS touched
    int e = (blockIdx.x - g1b) * 512 + tid;
    if (e < E) atomicAdd(&cnt[dst[e]], 1);
    return;
  }

  const int wave = tid >> 6;
  const int lane = tid & 63;
  const int l16 = lane & 15;
  const int quad = lane >> 4;
  const int m0 = blockIdx.x * 64;

  // ---- A staging: pure DMA of min(64, N-m0)*Ka floats (contiguous region) ----
  {
    int rows = N - m0;
    if (rows > 64) rows = 64;
    const int nwords = rows * Ka;                // f32 words
    const float* __restrict__ gsrc = x + (size_t)m0 * Ka;
    const int nchunks = nwords >> 8;             // 256 words = 1KB per wave-issue
    for (int ch = wave; ch < nchunks; ch += 8) {
      __builtin_amdgcn_global_load_lds(
          (gvoid_t*)(gsrc + ch * 256 + lane * 4),
          (svoid_t*)(&Af[ch * 256]), 16, 0, 0);
    }
    // tail (< 256 words): guarded per-lane word copy
    for (int i = (nchunks << 8) + tid; i < nwords; i += 512) {
      Af[i] = gsrc[i];
    }
  }

  f32x4 acc[4] = {};
  const int wr = wave >> 1;   // row group 0..3 (16 rows each)
  const int wc = wave & 1;    // col half 0..1 (64 cols each)
  const int wn = tid >> 2;
  const int wseg = tid & 3;
#pragma unroll
  for (int kc = 0; kc < 4; ++kc) {
    __syncthreads();  // (kc==0: also drains the A DMA via compiler vmcnt(0))
    *(uint4*)&Wl[wn * 72 + wseg * 16] =
        *(const uint4*)(Wt + (size_t)wn * 256 + kc * 64 + wseg * 16);
    *(uint4*)&Wl[wn * 72 + wseg * 16 + 8] =
        *(const uint4*)(Wt + (size_t)wn * 256 + kc * 64 + wseg * 16 + 8);
    __syncthreads();
#pragma unroll
    for (int s = 0; s < 2; ++s) {
      const int koff = kc * 64 + s * 32 + quad * 8;
      bf16x8 a = {};
      const float* ap = &Af[(wr * 16 + l16) * Ka + koff];
      if (koff + 8 <= Ka) {
#pragma unroll
        for (int j = 0; j < 8; ++j) {
          __hip_bfloat16 h = __float2bfloat16(ap[j]);
          a[j] = *(__bf16*)&h;
        }
      } else if (koff < Ka) {
#pragma unroll
        for (int j = 0; j < 8; ++j) {
          if (koff + j < Ka) {
            __hip_bfloat16 h = __float2bfloat16(ap[j]);
            a[j] = *(__bf16*)&h;
          }
        }
      }
      const int wof = s * 32 + quad * 8;
#pragma unroll
      for (int c = 0; c < 4; ++c) {
        bf16x8 b = *(const bf16x8*)&Wl[(wc * 64 + c * 16 + l16) * 72 + wof];
        acc[c] = __builtin_amdgcn_mfma_f32_16x16x32_bf16(a, b, acc[c], 0, 0, 0);
      }
    }
  }

  float bv[4];
#pragma unroll
  for (int c = 0; c < 4; ++c) bv[c] = bias[wc * 64 + c * 16 + l16];
#pragma unroll
  for (int reg = 0; reg < 4; ++reg) {
    int row = m0 + wr * 16 + quad * 4 + reg;
    if (row < N) {
#pragma unroll
      for (int c = 0; c < 4; ++c) {
        float v = acc[c][reg] + bv[c];
        v = v >= 0.f ? v : 0.01f * v;
        __hip_bfloat16 h = __float2bfloat16(v);
        C[(size_t)row * 128 + wc * 64 + c * 16 + l16] = *(ushort*)&h;
      }
    }
  }
}

// ---------------- MFMA GEMM (bf16 A, K=128): C = A @ Wt^T ----------------
// MODE: 1 = bf16 + bias; 3 = fused leaky(.+bias)@W2 + b2 -> out[N,2] f32.
// (byte-identical to R9)

template <int MODE>
__global__ __launch_bounds__(512, 4) void mgemm_k(const ushort* __restrict__ A,
                                                  const ushort* __restrict__ Wt,
                                                  const float* __restrict__ bias,
                                                  const float* __restrict__ W2,
                                                  const float* __restrict__ b2,
                                                  void* __restrict__ C, int N) {
  __shared__ uint4 Al[128 * 16];
  __shared__ uint4 Wl[128 * 16];
  const int tid = threadIdx.x;
  const int wave = tid >> 6;
  const int lane = tid & 63;
  const int l16 = lane & 15;
  const int quad = lane >> 4;
  const int m0 = blockIdx.x * 128;

  f32x4 acc[8] = {};
  const int r_s = tid >> 4;
  const int j8 = tid & 15;
#pragma unroll
  for (int it = 0; it < 4; ++it) {
    int m = it * 32 + r_s;
    Al[m * 16 + (j8 ^ (m & 15))] = *(const uint4*)(A + (size_t)(m0 + m) * 128 + j8 * 8);
  }
#pragma unroll
  for (int it = 0; it < 4; ++it) {
    int n = it * 32 + r_s;
    Wl[n * 16 + (j8 ^ (n & 15))] = *(const uint4*)(Wt + (size_t)n * 128 + j8 * 8);
  }
  __syncthreads();
#pragma unroll
  for (int s = 0; s < 4; ++s) {
    const int j = s * 4 + quad;
    const int arow = wave * 16 + l16;
    bf16x8 a = *(const bf16x8*)&Al[arow * 16 + (j ^ (arow & 15))];
#pragma unroll
    for (int c = 0; c < 8; ++c) {
      const int brow = c * 16 + l16;
      bf16x8 b = *(const bf16x8*)&Wl[brow * 16 + (j ^ (brow & 15))];
      acc[c] = __builtin_amdgcn_mfma_f32_16x16x32_bf16(a, b, acc[c], 0, 0, 0);
    }
  }

  float bv[8];
#pragma unroll
  for (int c = 0; c < 8; ++c) bv[c] = bias[c * 16 + l16];

  if constexpr (MODE == 3) {
    float w20[8], w21[8];
#pragma unroll
    for (int c = 0; c < 8; ++c) {
      int colj = c * 16 + l16;
      w20[c] = W2[colj * 2 + 0];
      w21[c] = W2[colj * 2 + 1];
    }
    float bb0 = b2[0], bb1 = b2[1];
#pragma unroll
    for (int reg = 0; reg < 4; ++reg) {
      float o0 = 0.f, o1 = 0.f;
#pragma unroll
      for (int c = 0; c < 8; ++c) {
        float v = acc[c][reg] + bv[c];
        v = v >= 0.f ? v : 0.01f * v;
        o0 = fmaf(v, w20[c], o0);
        o1 = fmaf(v, w21[c], o1);
      }
      o0 += __shfl_xor(o0, 1); o0 += __shfl_xor(o0, 2);
      o0 += __shfl_xor(o0, 4); o0 += __shfl_xor(o0, 8);
      o1 += __shfl_xor(o1, 1); o1 += __shfl_xor(o1, 2);
      o1 += __shfl_xor(o1, 4); o1 += __shfl_xor(o1, 8);
      int row = m0 + wave * 16 + quad * 4 + reg;
      if (l16 == 0 && row < N)
        *(float2*)((float*)C + (size_t)row * 2) = make_float2(o0 + bb0, o1 + bb1);
    }
    return;
  }

#pragma unroll
  for (int reg = 0; reg < 4; ++reg) {
    int row = m0 + wave * 16 + quad * 4 + reg;
    if (row < N) {
#pragma unroll
      for (int c = 0; c < 8; ++c) {
        float v = acc[c][reg] + bv[c];
        __hip_bfloat16 h = __float2bfloat16(v);
        ((ushort*)C)[(size_t)row * 128 + c * 16 + l16] = *(ushort*)&h;
      }
    }
  }
}

// ---------------- CSR-pull aggregation, bf16 -> bf16 ----------------
// R9's proven 4+2+1 unroll (R16's unroll-8 reverted: +48 live VGPRs was the
// only mechanism-bearing suspect for the 347->353 drift).

__global__ __launch_bounds__(256) void agg_k(const ushort* __restrict__ T,
                                             const float* __restrict__ dinv,
                                             const int* __restrict__ rp,
                                             const int2* __restrict__ ew,
                                             ushort* __restrict__ O, int N) {
  int l = threadIdx.x & 15;
  int node = blockIdx.x * 16 + (threadIdx.x >> 4);
  if (node >= N) return;
  float di = dinv[node];
  float dsq = di * di;
  const uint4* T4 = (const uint4*)T;
  float a[8];
  {
    uint4 sv = T4[(size_t)node * 16 + l];
    uint u[4] = {sv.x, sv.y, sv.z, sv.w};
#pragma unroll
    for (int p = 0; p < 4; ++p) {
      a[2 * p + 0] = __uint_as_float(u[p] << 16) * dsq;
      a[2 * p + 1] = __uint_as_float(u[p] & 0xFFFF0000u) * dsq;
    }
  }
  int e = rp[node];
  const int e1 = rp[node + 1];
  for (; e + 4 <= e1; e += 4) {
    int2 p0 = ew[e + 0], p1 = ew[e + 1], p2 = ew[e + 2], p3 = ew[e + 3];
    uint4 v0 = T4[(size_t)p0.x * 16 + l];
    uint4 v1 = T4[(size_t)p1.x * 16 + l];
    uint4 v2 = T4[(size_t)p2.x * 16 + l];
    uint4 v3 = T4[(size_t)p3.x * 16 + l];
    float w0 = __int_as_float(p0.y), w1 = __int_as_float(p1.y);
    float w2 = __int_as_float(p2.y), w3 = __int_as_float(p3.y);
    uint u0[4] = {v0.x, v0.y, v0.z, v0.w};
    uint u1[4] = {v1.x, v1.y, v1.z, v1.w};
    uint u2[4] = {v2.x, v2.y, v2.z, v2.w};
    uint u3[4] = {v3.x, v3.y, v3.z, v3.w};
#pragma unroll
    for (int p = 0; p < 4; ++p) {
      a[2 * p + 0] = fmaf(__uint_as_float(u0[p] << 16), w0, a[2 * p + 0]);
      a[2 * p + 1] = fmaf(__uint_as_float(u0[p] & 0xFFFF0000u), w0, a[2 * p + 1]);
      a[2 * p + 0] = fmaf(__uint_as_float(u1[p] << 16), w1, a[2 * p + 0]);
      a[2 * p + 1] = fmaf(__uint_as_float(u1[p] & 0xFFFF0000u), w1, a[2 * p + 1]);
      a[2 * p + 0] = fmaf(__uint_as_float(u2[p] << 16), w2, a[2 * p + 0]);
      a[2 * p + 1] = fmaf(__uint_as_float(u2[p] & 0xFFFF0000u), w2, a[2 * p + 1]);
      a[2 * p + 0] = fmaf(__uint_as_float(u3[p] << 16), w3, a[2 * p + 0]);
      a[2 * p + 1] = fmaf(__uint_as_float(u3[p] & 0xFFFF0000u), w3, a[2 * p + 1]);
    }
  }
  if (e + 2 <= e1) {
    int2 p0 = ew[e + 0], p1 = ew[e + 1];
    uint4 v0 = T4[(size_t)p0.x * 16 + l];
    uint4 v1 = T4[(size_t)p1.x * 16 + l];
    float w0 = __int_as_float(p0.y), w1 = __int_as_float(p1.y);
    uint u0[4] = {v0.x, v0.y, v0.z, v0.w};
    uint u1[4] = {v1.x, v1.y, v1.z, v1.w};
#pragma unroll
    for (int p = 0; p < 4; ++p) {
      a[2 * p + 0] = fmaf(__uint_as_float(u0[p] << 16), w0, a[2 * p + 0]);
      a[2 * p + 1] = fmaf(__uint_as_float(u0[p] & 0xFFFF0000u), w0, a[2 * p + 1]);
      a[2 * p + 0] = fmaf(__uint_as_float(u1[p] << 16), w1, a[2 * p + 0]);
      a[2 * p + 1] = fmaf(__uint_as_float(u1[p] & 0xFFFF0000u), w1, a[2 * p + 1]);
    }
    e += 2;
  }
  if (e < e1) {
    int2 pw = ew[e];
    float w = __int_as_float(pw.y);
    uint4 v = T4[(size_t)pw.x * 16 + l];
    uint u[4] = {v.x, v.y, v.z, v.w};
#pragma unroll
    for (int p = 0; p < 4; ++p) {
      a[2 * p + 0] = fmaf(__uint_as_float(u[p] << 16), w, a[2 * p + 0]);
      a[2 * p + 1] = fmaf(__uint_as_float(u[p] & 0xFFFF0000u), w, a[2 * p + 1]);
    }
  }
  union { uint4 v; ushort s[8]; } uo;
#pragma unroll
  for (int j = 0; j < 8; ++j) {
    __hip_bfloat16 h = __float2bfloat16(a[j]);
    uo.s[j] = *(ushort*)&h;
  }
  ((uint4*)O)[(size_t)node * 16 + l] = uo.v;
}

// ---------------- launch ----------------

extern "C" void kernel_launch(void* const* d_in, const int* in_sizes, int n_in,
                              void* d_out, int out_size, void* d_ws, size_t ws_size,
                              hipStream_t stream) {
  const float* x = (const float*)d_in[0];
  const int* ei = (const int*)d_in[1];
  const float* W_in = (const float*)d_in[3];
  const float* b_in = (const float*)d_in[4];
  const float* W_g  = (const float*)d_in[5];
  const float* b_g  = (const float*)d_in[6];
  const float* W_o1 = (const float*)d_in[7];
  const float* b_o1 = (const float*)d_in[8];
  const float* W_o2 = (const float*)d_in[9];
  const float* b_o2 = (const float*)d_in[10];

  const int D = in_sizes[4];        // 128
  const int ND = in_sizes[3] / D;   // 239
  const int N = in_sizes[0] / ND;   // 100000
  const int E = in_sizes[2];        // 640000
  const int* src = ei;
  const int* dst = ei + E;

  const int N_pad = ((N + 127) / 128) * 128;
  const size_t np = (size_t)N_pad;

  ushort* hA = (ushort*)d_ws;                 // np*128 bf16
  ushort* hB = hA + np * 128;                 // np*128 bf16
  ushort* Wt_in = hB + np * 128;              // 128*256 bf16
  ushort* Wt_g  = Wt_in + 128 * 256;          // 128*128
  ushort* Wt_o1 = Wt_g + 128 * 128;           // 128*128
  float* dinv = (float*)(Wt_o1 + 128 * 128);  // N f32
  int* cnt  = (int*)(dinv + N);
  int* rp   = cnt + N;
  int* bsum = rp + (N + 1);
  int2* ew  = (int2*)(((size_t)(bsum + 1024) + 7) & ~(size_t)7);

  const int NB = (N + 1023) / 1024;

  wtr_all_k<<<(65536 + N + 255) / 256, 256, 0, stream>>>(
      W_in, W_g, W_o1, Wt_in, Wt_g, Wt_o1, cnt, N, ND);

  const int g1blocks = (N + 63) / 64;
  const int hblocks = (E + 511) / 512;
  gemm1h_k<<<g1blocks + hblocks, 512, 0, stream>>>(
      x, Wt_in, b_in, hA, N, ND, g1blocks, dst, cnt, E);

  scan1_k<<<NB, 256, 0, stream>>>(cnt, rp, bsum, N);
  scan2_k<<<1, 256, 0, stream>>>(bsum, NB);
  scan3_k<<<(N + 255) / 256, 256, 0, stream>>>(rp, cnt /*pos*/, bsum, dinv, N, E);
  fill_k<<<(E + 255) / 256, 256, 0, stream>>>(src, dst, dinv, cnt, ew, E);

  const int gblocks = N_pad / 128;
  const int ablocks = (N + 15) / 16;
  agg_k<<<ablocks, 256, 0, stream>>>(hA, dinv, rp, ew, hB, N);
  mgemm_k<1><<<gblocks, 512, 0, stream>>>(hB, Wt_g, b_g, nullptr, nullptr, hA, N);
  agg_k<<<ablocks, 256, 0, stream>>>(hA, dinv, rp, ew, hB, N);
  mgemm_k<1><<<gblocks, 512, 0, stream>>>(hB, Wt_g, b_g, nullptr, nullptr, hA, N);
  mgemm_k<3><<<gblocks, 512, 0, stream>>>(hA, Wt_o1, b_o1, W_o2, b_o2, d_out, N);
}

// Round 11
// 334.689 us; speedup vs baseline: 1.0840x; 1.0047x over previous
//
#include <hip/hip_runtime.h>
#include <hip/hip_bf16.h>

// GCN pipeline on MI355X — MFMA bf16 GEMMs, fp32 accumulate, bf16 dataflow.
// R18: one-variable change over R17 (336.3us best): hist blocks moved to the
//      FRONT of gemm1h's grid. R17 appended them after the 1563 GEMM blocks,
//      so the 1250 hist blocks (each reserving the kernel's 80KB static LDS
//      -> 2 blocks/CU) ran as a ~20us serial tail. Hist-first drains them in
//      ~5-8us across the CU array and overlaps the seam with the first GEMM
//      blocks. Everything else byte-identical to R17.

typedef __attribute__((ext_vector_type(8))) __bf16 bf16x8;
typedef __attribute__((ext_vector_type(4))) float f32x4;

typedef __attribute__((address_space(1))) const void gvoid_t;
typedef __attribute__((address_space(3))) void svoid_t;

// All 3 weight transposes + cnt zeroing in one dispatch.
// seg0 [0, 32768):        W_in [ND][128] -> Wt_in [128][256] (zero pad k>=ND)
// seg1 [32768, 49152):    W_g  [128][128] -> Wt_g  [128][128]
// seg2 [49152, 65536):    W_o1 [128][128] -> Wt_o1 [128][128]
// seg3 [65536, 65536+N):  cnt[i] = 0
__global__ __launch_bounds__(256) void wtr_all_k(const float* __restrict__ W_in,
                                                 const float* __restrict__ W_g,
                                                 const float* __restrict__ W_o1,
                                                 ushort* __restrict__ Wt_in,
                                                 ushort* __restrict__ Wt_g,
                                                 ushort* __restrict__ Wt_o1,
                                                 int* __restrict__ cnt, int N, int ND) {
  int idx = blockIdx.x * 256 + threadIdx.x;
  if (idx < 128 * 256) {
    int n = idx >> 8, k = idx & 255;
    float v = (k < ND) ? W_in[(size_t)k * 128 + n] : 0.f;
    __hip_bfloat16 h = __float2bfloat16(v);
    Wt_in[idx] = *(ushort*)&h;
  } else if (idx < 128 * 256 + 128 * 128) {
    int j = idx - 128 * 256;
    int n = j >> 7, k = j & 127;
    __hip_bfloat16 h = __float2bfloat16(W_g[(size_t)k * 128 + n]);
    Wt_g[j] = *(ushort*)&h;
  } else if (idx < 128 * 256 + 2 * 128 * 128) {
    int j = idx - 128 * 256 - 128 * 128;
    int n = j >> 7, k = j & 127;
    __hip_bfloat16 h = __float2bfloat16(W_o1[(size_t)k * 128 + n]);
    Wt_o1[j] = *(ushort*)&h;
  } else {
    int i = idx - 65536;
    if (i < N) cnt[i] = 0;
  }
}

// ---------------- CSR build ----------------

__global__ __launch_bounds__(256) void scan1_k(const int* __restrict__ cnt, int* __restrict__ rp,
                                               int* __restrict__ bsum, int N) {
  __shared__ int sd[256];
  int t = threadIdx.x;
  int base = blockIdx.x * 1024 + t * 4;
  int v0 = (base + 0 < N) ? cnt[base + 0] : 0;
  int v1 = (base + 1 < N) ? cnt[base + 1] : 0;
  int v2 = (base + 2 < N) ? cnt[base + 2] : 0;
  int v3 = (base + 3 < N) ? cnt[base + 3] : 0;
  int ts = v0 + v1 + v2 + v3;
  sd[t] = ts;
  __syncthreads();
  for (int off = 1; off < 256; off <<= 1) {
    int y = (t >= off) ? sd[t - off] : 0;
    __syncthreads();
    sd[t] += y;
    __syncthreads();
  }
  int x = sd[t] - ts;
  if (t == 255) bsum[blockIdx.x] = sd[255];
  if (base + 0 < N) rp[base + 0] = x; x += v0;
  if (base + 1 < N) rp[base + 1] = x; x += v1;
  if (base + 2 < N) rp[base + 2] = x; x += v2;
  if (base + 3 < N) rp[base + 3] = x;
}

__global__ __launch_bounds__(256) void scan2_k(int* __restrict__ bsum, int NB) {
  __shared__ int sd[256];
  int t = threadIdx.x;
  int base = t * 4;
  int v0 = (base + 0 < NB) ? bsum[base + 0] : 0;
  int v1 = (base + 1 < NB) ? bsum[base + 1] : 0;
  int v2 = (base + 2 < NB) ? bsum[base + 2] : 0;
  int v3 = (base + 3 < NB) ? bsum[base + 3] : 0;
  int ts = v0 + v1 + v2 + v3;
  sd[t] = ts;
  __syncthreads();
  for (int off = 1; off < 256; off <<= 1) {
    int y = (t >= off) ? sd[t - off] : 0;
    __syncthreads();
    sd[t] += y;
    __syncthreads();
  }
  int x = sd[t] - ts;
  if (base + 0 < NB) bsum[base + 0] = x; x += v0;
  if (base + 1 < NB) bsum[base + 1] = x; x += v1;
  if (base + 2 < NB) bsum[base + 2] = x; x += v2;
  if (base + 3 < NB) bsum[base + 3] = x;
}

__global__ __launch_bounds__(256) void scan3_k(int* __restrict__ rp, int* __restrict__ pos,
                                               const int* __restrict__ bsum,
                                               float* __restrict__ dinv, int N, int E) {
  int i = blockIdx.x * 256 + threadIdx.x;
  if (i < N) {
    int c = pos[i];  // pos aliases cnt: still the original count here
    int v = rp[i] + bsum[i >> 10];
    dinv[i] = rsqrtf((float)c + 1.0f);
    rp[i] = v;
    pos[i] = v;
  }
  if (i == 0) rp[N] = E;
}

__global__ __launch_bounds__(256) void fill_k(const int* __restrict__ src, const int* __restrict__ dst,
                                              const float* __restrict__ dinv,
                                              int* __restrict__ pos, int2* __restrict__ ew, int E) {
  int e = blockIdx.x * 256 + threadIdx.x;
  if (e < E) {
    int d = dst[e];
    int s = src[e];
    int idx = atomicAdd(&pos[d], 1);
    ew[idx] = make_int2(s, __float_as_int(dinv[s] * dinv[d]));
  }
}

// ---------------- GEMM1 (+ fused hist): blocks [0, hb) do the degree
// histogram (short, latency-bound — drain first and overlap the seam with
// the first GEMM blocks); blocks [hb, hb + g1b) do the MFMA GEMM.
// GEMM body byte-identical to R9/R17. ----------

__global__ __launch_bounds__(512, 4) void gemm1h_k(const float* __restrict__ x,
                                                   const ushort* __restrict__ Wt,
                                                   const float* __restrict__ bias,
                                                   ushort* __restrict__ C, int N, int Ka,
                                                   int hb,
                                                   const int* __restrict__ dst,
                                                   int* __restrict__ cnt, int E) {
  __shared__ float Af[64 * 239 + 8];   // 61,216 B (flat f32 image of the x tile)
  __shared__ ushort Wl[128 * 72];      // 18,432 B
  const int tid = threadIdx.x;

  if (blockIdx.x < hb) {
    // hist segment: no barriers, no LDS touched
    int e = blockIdx.x * 512 + tid;
    if (e < E) atomicAdd(&cnt[dst[e]], 1);
    return;
  }

  const int wave = tid >> 6;
  const int lane = tid & 63;
  const int l16 = lane & 15;
  const int quad = lane >> 4;
  const int m0 = (blockIdx.x - hb) * 64;

  // ---- A staging: pure DMA of min(64, N-m0)*Ka floats (contiguous region) ----
  {
    int rows = N - m0;
    if (rows > 64) rows = 64;
    const int nwords = rows * Ka;                // f32 words
    const float* __restrict__ gsrc = x + (size_t)m0 * Ka;
    const int nchunks = nwords >> 8;             // 256 words = 1KB per wave-issue
    for (int ch = wave; ch < nchunks; ch += 8) {
      __builtin_amdgcn_global_load_lds(
          (gvoid_t*)(gsrc + ch * 256 + lane * 4),
          (svoid_t*)(&Af[ch * 256]), 16, 0, 0);
    }
    // tail (< 256 words): guarded per-lane word copy
    for (int i = (nchunks << 8) + tid; i < nwords; i += 512) {
      Af[i] = gsrc[i];
    }
  }

  f32x4 acc[4] = {};
  const int wr = wave >> 1;   // row group 0..3 (16 rows each)
  const int wc = wave & 1;    // col half 0..1 (64 cols each)
  const int wn = tid >> 2;
  const int wseg = tid & 3;
#pragma unroll
  for (int kc = 0; kc < 4; ++kc) {
    __syncthreads();  // (kc==0: also drains the A DMA via compiler vmcnt(0))
    *(uint4*)&Wl[wn * 72 + wseg * 16] =
        *(const uint4*)(Wt + (size_t)wn * 256 + kc * 64 + wseg * 16);
    *(uint4*)&Wl[wn * 72 + wseg * 16 + 8] =
        *(const uint4*)(Wt + (size_t)wn * 256 + kc * 64 + wseg * 16 + 8);
    __syncthreads();
#pragma unroll
    for (int s = 0; s < 2; ++s) {
      const int koff = kc * 64 + s * 32 + quad * 8;
      bf16x8 a = {};
      const float* ap = &Af[(wr * 16 + l16) * Ka + koff];
      if (koff + 8 <= Ka) {
#pragma unroll
        for (int j = 0; j < 8; ++j) {
          __hip_bfloat16 h = __float2bfloat16(ap[j]);
          a[j] = *(__bf16*)&h;
        }
      } else if (koff < Ka) {
#pragma unroll
        for (int j = 0; j < 8; ++j) {
          if (koff + j < Ka) {
            __hip_bfloat16 h = __float2bfloat16(ap[j]);
            a[j] = *(__bf16*)&h;
          }
        }
      }
      const int wof = s * 32 + quad * 8;
#pragma unroll
      for (int c = 0; c < 4; ++c) {
        bf16x8 b = *(const bf16x8*)&Wl[(wc * 64 + c * 16 + l16) * 72 + wof];
        acc[c] = __builtin_amdgcn_mfma_f32_16x16x32_bf16(a, b, acc[c], 0, 0, 0);
      }
    }
  }

  float bv[4];
#pragma unroll
  for (int c = 0; c < 4; ++c) bv[c] = bias[wc * 64 + c * 16 + l16];
#pragma unroll
  for (int reg = 0; reg < 4; ++reg) {
    int row = m0 + wr * 16 + quad * 4 + reg;
    if (row < N) {
#pragma unroll
      for (int c = 0; c < 4; ++c) {
        float v = acc[c][reg] + bv[c];
        v = v >= 0.f ? v : 0.01f * v;
        __hip_bfloat16 h = __float2bfloat16(v);
        C[(size_t)row * 128 + wc * 64 + c * 16 + l16] = *(ushort*)&h;
      }
    }
  }
}

// ---------------- MFMA GEMM (bf16 A, K=128): C = A @ Wt^T ----------------
// MODE: 1 = bf16 + bias; 3 = fused leaky(.+bias)@W2 + b2 -> out[N,2] f32.
// (byte-identical to R9)

template <int MODE>
__global__ __launch_bounds__(512, 4) void mgemm_k(const ushort* __restrict__ A,
                                                  const ushort* __restrict__ Wt,
                                                  const float* __restrict__ bias,
                                                  const float* __restrict__ W2,
                                                  const float* __restrict__ b2,
                                                  void* __restrict__ C, int N) {
  __shared__ uint4 Al[128 * 16];
  __shared__ uint4 Wl[128 * 16];
  const int tid = threadIdx.x;
  const int wave = tid >> 6;
  const int lane = tid & 63;
  const int l16 = lane & 15;
  const int quad = lane >> 4;
  const int m0 = blockIdx.x * 128;

  f32x4 acc[8] = {};
  const int r_s = tid >> 4;
  const int j8 = tid & 15;
#pragma unroll
  for (int it = 0; it < 4; ++it) {
    int m = it * 32 + r_s;
    Al[m * 16 + (j8 ^ (m & 15))] = *(const uint4*)(A + (size_t)(m0 + m) * 128 + j8 * 8);
  }
#pragma unroll
  for (int it = 0; it < 4; ++it) {
    int n = it * 32 + r_s;
    Wl[n * 16 + (j8 ^ (n & 15))] = *(const uint4*)(Wt + (size_t)n * 128 + j8 * 8);
  }
  __syncthreads();
#pragma unroll
  for (int s = 0; s < 4; ++s) {
    const int j = s * 4 + quad;
    const int arow = wave * 16 + l16;
    bf16x8 a = *(const bf16x8*)&Al[arow * 16 + (j ^ (arow & 15))];
#pragma unroll
    for (int c = 0; c < 8; ++c) {
      const int brow = c * 16 + l16;
      bf16x8 b = *(const bf16x8*)&Wl[brow * 16 + (j ^ (brow & 15))];
      acc[c] = __builtin_amdgcn_mfma_f32_16x16x32_bf16(a, b, acc[c], 0, 0, 0);
    }
  }

  float bv[8];
#pragma unroll
  for (int c = 0; c < 8; ++c) bv[c] = bias[c * 16 + l16];

  if constexpr (MODE == 3) {
    float w20[8], w21[8];
#pragma unroll
    for (int c = 0; c < 8; ++c) {
      int colj = c * 16 + l16;
      w20[c] = W2[colj * 2 + 0];
      w21[c] = W2[colj * 2 + 1];
    }
    float bb0 = b2[0], bb1 = b2[1];
#pragma unroll
    for (int reg = 0; reg < 4; ++reg) {
      float o0 = 0.f, o1 = 0.f;
#pragma unroll
      for (int c = 0; c < 8; ++c) {
        float v = acc[c][reg] + bv[c];
        v = v >= 0.f ? v : 0.01f * v;
        o0 = fmaf(v, w20[c], o0);
        o1 = fmaf(v, w21[c], o1);
      }
      o0 += __shfl_xor(o0, 1); o0 += __shfl_xor(o0, 2);
      o0 += __shfl_xor(o0, 4); o0 += __shfl_xor(o0, 8);
      o1 += __shfl_xor(o1, 1); o1 += __shfl_xor(o1, 2);
      o1 += __shfl_xor(o1, 4); o1 += __shfl_xor(o1, 8);
      int row = m0 + wave * 16 + quad * 4 + reg;
      if (l16 == 0 && row < N)
        *(float2*)((float*)C + (size_t)row * 2) = make_float2(o0 + bb0, o1 + bb1);
    }
    return;
  }

#pragma unroll
  for (int reg = 0; reg < 4; ++reg) {
    int row = m0 + wave * 16 + quad * 4 + reg;
    if (row < N) {
#pragma unroll
      for (int c = 0; c < 8; ++c) {
        float v = acc[c][reg] + bv[c];
        __hip_bfloat16 h = __float2bfloat16(v);
        ((ushort*)C)[(size_t)row * 128 + c * 16 + l16] = *(ushort*)&h;
      }
    }
  }
}

// ---------------- CSR-pull aggregation, bf16 -> bf16 ----------------
// R9's proven 4+2+1 unroll.

__global__ __launch_bounds__(256) void agg_k(const ushort* __restrict__ T,
                                             const float* __restrict__ dinv,
                                             const int* __restrict__ rp,
                                             const int2* __restrict__ ew,
                                             ushort* __restrict__ O, int N) {
  int l = threadIdx.x & 15;
  int node = blockIdx.x * 16 + (threadIdx.x >> 4);
  if (node >= N) return;
  float di = dinv[node];
  float dsq = di * di;
  const uint4* T4 = (const uint4*)T;
  float a[8];
  {
    uint4 sv = T4[(size_t)node * 16 + l];
    uint u[4] = {sv.x, sv.y, sv.z, sv.w};
#pragma unroll
    for (int p = 0; p < 4; ++p) {
      a[2 * p + 0] = __uint_as_float(u[p] << 16) * dsq;
      a[2 * p + 1] = __uint_as_float(u[p] & 0xFFFF0000u) * dsq;
    }
  }
  int e = rp[node];
  const int e1 = rp[node + 1];
  for (; e + 4 <= e1; e += 4) {
    int2 p0 = ew[e + 0], p1 = ew[e + 1], p2 = ew[e + 2], p3 = ew[e + 3];
    uint4 v0 = T4[(size_t)p0.x * 16 + l];
    uint4 v1 = T4[(size_t)p1.x * 16 + l];
    uint4 v2 = T4[(size_t)p2.x * 16 + l];
    uint4 v3 = T4[(size_t)p3.x * 16 + l];
    float w0 = __int_as_float(p0.y), w1 = __int_as_float(p1.y);
    float w2 = __int_as_float(p2.y), w3 = __int_as_float(p3.y);
    uint u0[4] = {v0.x, v0.y, v0.z, v0.w};
    uint u1[4] = {v1.x, v1.y, v1.z, v1.w};
    uint u2[4] = {v2.x, v2.y, v2.z, v2.w};
    uint u3[4] = {v3.x, v3.y, v3.z, v3.w};
#pragma unroll
    for (int p = 0; p < 4; ++p) {
      a[2 * p + 0] = fmaf(__uint_as_float(u0[p] << 16), w0, a[2 * p + 0]);
      a[2 * p + 1] = fmaf(__uint_as_float(u0[p] & 0xFFFF0000u), w0, a[2 * p + 1]);
      a[2 * p + 0] = fmaf(__uint_as_float(u1[p] << 16), w1, a[2 * p + 0]);
      a[2 * p + 1] = fmaf(__uint_as_float(u1[p] & 0xFFFF0000u), w1, a[2 * p + 1]);
      a[2 * p + 0] = fmaf(__uint_as_float(u2[p] << 16), w2, a[2 * p + 0]);
      a[2 * p + 1] = fmaf(__uint_as_float(u2[p] & 0xFFFF0000u), w2, a[2 * p + 1]);
      a[2 * p + 0] = fmaf(__uint_as_float(u3[p] << 16), w3, a[2 * p + 0]);
      a[2 * p + 1] = fmaf(__uint_as_float(u3[p] & 0xFFFF0000u), w3, a[2 * p + 1]);
    }
  }
  if (e + 2 <= e1) {
    int2 p0 = ew[e + 0], p1 = ew[e + 1];
    uint4 v0 = T4[(size_t)p0.x * 16 + l];
    uint4 v1 = T4[(size_t)p1.x * 16 + l];
    float w0 = __int_as_float(p0.y), w1 = __int_as_float(p1.y);
    uint u0[4] = {v0.x, v0.y, v0.z, v0.w};
    uint u1[4] = {v1.x, v1.y, v1.z, v1.w};
#pragma unroll
    for (int p = 0; p < 4; ++p) {
      a[2 * p + 0] = fmaf(__uint_as_float(u0[p] << 16), w0, a[2 * p + 0]);
      a[2 * p + 1] = fmaf(__uint_as_float(u0[p] & 0xFFFF0000u), w0, a[2 * p + 1]);
      a[2 * p + 0] = fmaf(__uint_as_float(u1[p] << 16), w1, a[2 * p + 0]);
      a[2 * p + 1] = fmaf(__uint_as_float(u1[p] & 0xFFFF0000u), w1, a[2 * p + 1]);
    }
    e += 2;
  }
  if (e < e1) {
    int2 pw = ew[e];
    float w = __int_as_float(pw.y);
    uint4 v = T4[(size_t)pw.x * 16 + l];
    uint u[4] = {v.x, v.y, v.z, v.w};
#pragma unroll
    for (int p = 0; p < 4; ++p) {
      a[2 * p + 0] = fmaf(__uint_as_float(u[p] << 16), w, a[2 * p + 0]);
      a[2 * p + 1] = fmaf(__uint_as_float(u[p] & 0xFFFF0000u), w, a[2 * p + 1]);
    }
  }
  union { uint4 v; ushort s[8]; } uo;
#pragma unroll
  for (int j = 0; j < 8; ++j) {
    __hip_bfloat16 h = __float2bfloat16(a[j]);
    uo.s[j] = *(ushort*)&h;
  }
  ((uint4*)O)[(size_t)node * 16 + l] = uo.v;
}

// ---------------- launch ----------------

extern "C" void kernel_launch(void* const* d_in, const int* in_sizes, int n_in,
                              void* d_out, int out_size, void* d_ws, size_t ws_size,
                              hipStream_t stream) {
  const float* x = (const float*)d_in[0];
  const int* ei = (const int*)d_in[1];
  const float* W_in = (const float*)d_in[3];
  const float* b_in = (const float*)d_in[4];
  const float* W_g  = (const float*)d_in[5];
  const float* b_g  = (const float*)d_in[6];
  const float* W_o1 = (const float*)d_in[7];
  const float* b_o1 = (const float*)d_in[8];
  const float* W_o2 = (const float*)d_in[9];
  const float* b_o2 = (const float*)d_in[10];

  const int D = in_sizes[4];        // 128
  const int ND = in_sizes[3] / D;   // 239
  const int N = in_sizes[0] / ND;   // 100000
  const int E = in_sizes[2];        // 640000
  const int* src = ei;
  const int* dst = ei + E;

  const int N_pad = ((N + 127) / 128) * 128;
  const size_t np = (size_t)N_pad;

  ushort* hA = (ushort*)d_ws;                 // np*128 bf16
  ushort* hB = hA + np * 128;                 // np*128 bf16
  ushort* Wt_in = hB + np * 128;              // 128*256 bf16
  ushort* Wt_g  = Wt_in + 128 * 256;          // 128*128
  ushort* Wt_o1 = Wt_g + 128 * 128;           // 128*128
  float* dinv = (float*)(Wt_o1 + 128 * 128);  // N f32
  int* cnt  = (int*)(dinv + N);
  int* rp   = cnt + N;
  int* bsum = rp + (N + 1);
  int2* ew  = (int2*)(((size_t)(bsum + 1024) + 7) & ~(size_t)7);

  const int NB = (N + 1023) / 1024;

  wtr_all_k<<<(65536 + N + 255) / 256, 256, 0, stream>>>(
      W_in, W_g, W_o1, Wt_in, Wt_g, Wt_o1, cnt, N, ND);

  const int g1blocks = (N + 63) / 64;
  const int hblocks = (E + 511) / 512;
  gemm1h_k<<<hblocks + g1blocks, 512, 0, stream>>>(
      x, Wt_in, b_in, hA, N, ND, hblocks, dst, cnt, E);

  scan1_k<<<NB, 256, 0, stream>>>(cnt, rp, bsum, N);
  scan2_k<<<1, 256, 0, stream>>>(bsum, NB);
  scan3_k<<<(N + 255) / 256, 256, 0, stream>>>(rp, cnt /*pos*/, bsum, dinv, N, E);
  fill_k<<<(E + 255) / 256, 256, 0, stream>>>(src, dst, dinv, cnt, ew, E);

  const int gblocks = N_pad / 128;
  const int ablocks = (N + 15) / 16;
  agg_k<<<ablocks, 256, 0, stream>>>(hA, dinv, rp, ew, hB, N);
  mgemm_k<1><<<gblocks, 512, 0, stream>>>(hB, Wt_g, b_g, nullptr, nullptr, hA, N);
  agg_k<<<ablocks, 256, 0, stream>>>(hA, dinv, rp, ew, hB, N);
  mgemm_k<1><<<gblocks, 512, 0, stream>>>(hB, Wt_g, b_g, nullptr, nullptr, hA, N);
  mgemm_k<3><<<gblocks, 512, 0, stream>>>(hA, Wt_o1, b_o1, W_o2, b_o2, d_out, N);
}